// Round 4
// baseline (8968.333 us; speedup 1.0000x reference)
//
#include <hip/hip_runtime.h>
#include <cstdint>
#include <cstddef>

#define NS   200000
#define CIN  64
#define HID  384
#define COUT 64
#define KV   9
#define BN_EPS 1e-5f

typedef unsigned short u16;  // bf16 bits

__device__ __forceinline__ float relu6f(float v) { return fminf(fmaxf(v, 0.f), 6.f); }

__device__ __forceinline__ float bf2f(u16 u) {
  union { unsigned int i; float f; } c; c.i = ((unsigned int)u) << 16; return c.f;
}
__device__ __forceinline__ u16 f2bf(float f) {
  union { float f; unsigned int i; } c; c.f = f;
  unsigned int x = c.i;
  return (u16)((x + 0x7FFFu + ((x >> 16) & 1u)) >> 16);  // RNE
}

// ---- storage-type polymorphic load/store ----
__device__ __forceinline__ float4 ld4(const float* p) { return *reinterpret_cast<const float4*>(p); }
__device__ __forceinline__ float4 ld4(const u16* p) {
  ushort4 u = *reinterpret_cast<const ushort4*>(p);
  return make_float4(bf2f(u.x), bf2f(u.y), bf2f(u.z), bf2f(u.w));
}
__device__ __forceinline__ void st4(float* p, float4 v) { *reinterpret_cast<float4*>(p) = v; }
__device__ __forceinline__ void st4(u16* p, float4 v) {
  ushort4 u; u.x = f2bf(v.x); u.y = f2bf(v.y); u.z = f2bf(v.z); u.w = f2bf(v.w);
  *reinterpret_cast<ushort4*>(p) = u;
}
__device__ __forceinline__ float ld1(const float* p) { return *p; }
__device__ __forceinline__ float ld1(const u16* p) { return bf2f(*p); }
__device__ __forceinline__ void st1(float* p, float v) { *p = v; }
__device__ __forceinline__ void st1(u16* p, float v) { *p = f2bf(v); }

// ---------------------------------------------------------------------------
// Mask layout detection + canonicalization to uint8.
// int32 0/1: bytes !=0 only at offset%4==0. float32 0/1.0f: bytes !=0 only at
// offsets %4 in {2,3} (0x80,0x3F). uint8: dense nonzero at all residues.
// ---------------------------------------------------------------------------
__global__ void k_detect(const uint8_t* __restrict__ raw, int* __restrict__ flag) {
  __shared__ int nz[4];
  if (threadIdx.x < 4) nz[threadIdx.x] = 0;
  __syncthreads();
  int cnt[4] = {0, 0, 0, 0};
  const uint8_t* p = raw + threadIdx.x * 16;   // 256 thr * 16B = 4096B scanned
#pragma unroll
  for (int j = 0; j < 16; ++j) if (p[j]) cnt[j & 3]++;
#pragma unroll
  for (int r = 0; r < 4; ++r) if (cnt[r]) atomicAdd(&nz[r], cnt[r]);
  __syncthreads();
  if (threadIdx.x == 0) {
    int f;
    if (nz[1] == 0 && nz[2] == 0 && nz[3] == 0) f = 0;       // int32
    else if (nz[0] == 0 && nz[1] == 0)          f = 2;       // float32
    else                                        f = 1;       // uint8
    *flag = f;
  }
}

__global__ __launch_bounds__(256)
void k_canon(const void* __restrict__ raw, const int* __restrict__ flag,
             uint8_t* __restrict__ cmask, int n) {
  const int e = blockIdx.x * 256 + threadIdx.x;
  if (e >= n) return;
  const int f = *flag;
  uint8_t v;
  if (f == 0)      v = ((const int*)raw)[e] != 0;
  else if (f == 1) v = ((const uint8_t*)raw)[e] != 0;
  else             v = ((const float*)raw)[e] != 0.f;
  cmask[e] = v;
}

// ---------------------------------------------------------------------------
// Kernel A: t1 = x @ w1 [NS x HID] (optional store), per-column sum/sumsq BN1.
// Tile 128x128, K=64. 256 threads, 8x8 register blocking.
// ---------------------------------------------------------------------------
template <typename TO, bool STORE>
__global__ __launch_bounds__(256, 2)
void k_gemm1(const float* __restrict__ x, const float* __restrict__ w1,
             TO* __restrict__ t1, float* __restrict__ stats1) {
  __shared__ float lds[8320 + 8192];
  float* __restrict__ Xs = lds;          // [128][65]
  float* __restrict__ Ws = lds + 8320;   // [64][128]
  const int row0 = blockIdx.x * 128;
  const int col0 = blockIdx.y * 128;
  const int tid  = threadIdx.x;

  {  // stage X tile [m][k], stride 65
    const int k4 = (tid & 15) * 4;
    const int mb = tid >> 4;
#pragma unroll
    for (int it = 0; it < 8; ++it) {
      const int m = mb + it * 16;
      const int r = row0 + m;
      float4 v = make_float4(0.f, 0.f, 0.f, 0.f);
      if (r < NS) v = *reinterpret_cast<const float4*>(x + (size_t)r * CIN + k4);
      float* p = Xs + m * 65 + k4;
      p[0] = v.x; p[1] = v.y; p[2] = v.z; p[3] = v.w;
    }
  }
  {  // stage W tile [k][n]
    const int n4 = (tid & 31) * 4;
    const int kb = tid >> 5;
#pragma unroll
    for (int it = 0; it < 8; ++it) {
      const int k = kb + it * 8;
      *reinterpret_cast<float4*>(Ws + k * 128 + n4) =
          *reinterpret_cast<const float4*>(w1 + k * HID + col0 + n4);
    }
  }
  __syncthreads();

  const int tx = tid & 15, ty = tid >> 4;
  float acc[8][8];
#pragma unroll
  for (int i = 0; i < 8; ++i)
#pragma unroll
    for (int j = 0; j < 8; ++j) acc[i][j] = 0.f;

#pragma unroll 8
  for (int k = 0; k < 64; ++k) {
    float a[8], b[8];
#pragma unroll
    for (int i = 0; i < 4; ++i) {
      a[i]     = Xs[(ty * 4 + i) * 65 + k];
      a[4 + i] = Xs[(64 + ty * 4 + i) * 65 + k];
    }
    float4 b0 = *reinterpret_cast<const float4*>(Ws + k * 128 + tx * 4);
    float4 b1 = *reinterpret_cast<const float4*>(Ws + k * 128 + 64 + tx * 4);
    b[0]=b0.x; b[1]=b0.y; b[2]=b0.z; b[3]=b0.w;
    b[4]=b1.x; b[5]=b1.y; b[6]=b1.z; b[7]=b1.w;
#pragma unroll
    for (int i = 0; i < 8; ++i)
#pragma unroll
      for (int j = 0; j < 8; ++j) acc[i][j] = fmaf(a[i], b[j], acc[i][j]);
  }

  if constexpr (STORE) {
#pragma unroll
    for (int i = 0; i < 8; ++i) {
      const int r = row0 + ((i < 4) ? (ty * 4 + i) : (64 + ty * 4 + i - 4));
      if (r < NS) {
        st4(t1 + (size_t)r * HID + col0 + tx * 4,
            make_float4(acc[i][0], acc[i][1], acc[i][2], acc[i][3]));
        st4(t1 + (size_t)r * HID + col0 + 64 + tx * 4,
            make_float4(acc[i][4], acc[i][5], acc[i][6], acc[i][7]));
      }
    }
  }

  float cs[8], cq[8];
#pragma unroll
  for (int j = 0; j < 8; ++j) {
    cs[j] = 0.f; cq[j] = 0.f;
#pragma unroll
    for (int i = 0; i < 8; ++i) { float v = acc[i][j]; cs[j] += v; cq[j] += v * v; }
  }
  __syncthreads();
  float* red = lds;  // [16][256]
#pragma unroll
  for (int j = 0; j < 8; ++j) {
    const int col = (j < 4) ? (tx * 4 + j) : (64 + tx * 4 + j - 4);
    red[ty * 256 + col * 2]     = cs[j];
    red[ty * 256 + col * 2 + 1] = cq[j];
  }
  __syncthreads();
  {
    float s = 0.f;
#pragma unroll
    for (int t = 0; t < 16; ++t) s += red[t * 256 + tid];
    const int col = tid >> 1, st = tid & 1;
    atomicAdd(stats1 + st * HID + col0 + col, s);
  }
}

// ---------------------------------------------------------------------------
// Kernel C: depthwise gather conv with BN1+relu6 on the fly (materialized t1).
// ---------------------------------------------------------------------------
template <typename TI, typename TO>
__global__ __launch_bounds__(384)
void k_dwconv(const TI* __restrict__ t1, const int* __restrict__ nidx,
              const uint8_t* __restrict__ cmask, const float* __restrict__ w2,
              const float* __restrict__ scale1, const float* __restrict__ shift1,
              TO* __restrict__ out2, float* __restrict__ stats2) {
  const int c  = threadIdx.x;
  const float s1 = scale1[c];
  const float b1 = shift1[c];
  float w2r[KV];
#pragma unroll
  for (int k = 0; k < KV; ++k) w2r[k] = w2[k * HID + c];

  const int rowBase = blockIdx.x * 64;
  float sum = 0.f, sq = 0.f;
  for (int r = 0; r < 64; ++r) {
    const int i = rowBase + r;
    const int*     ip = nidx  + (size_t)i * KV;
    const uint8_t* mp = cmask + (size_t)i * KV;
    float acc = 0.f;
#pragma unroll
    for (int k = 0; k < KV; ++k) {
      if (mp[k]) {  // block-uniform branch
        const int j = ip[k];
        const float v = ld1(t1 + (size_t)j * HID + c);
        const float h = relu6f(fmaf(v, s1, b1));
        acc = fmaf(h, w2r[k], acc);
      }
    }
    st1(out2 + (size_t)i * HID + c, acc);
    sum += acc; sq += acc * acc;
  }
  atomicAdd(stats2 + c,       sum);
  atomicAdd(stats2 + HID + c, sq);
}

// ---------------------------------------------------------------------------
// Kernel D: t3 = relu6(bn2(out2)) @ w3 -> d_out, plus BN3 stats.
// ---------------------------------------------------------------------------
template <typename TI>
__global__ __launch_bounds__(256, 3)
void k_gemm3(const TI* __restrict__ out2, const float* __restrict__ w3,
             const float* __restrict__ scale2, const float* __restrict__ shift2,
             float* __restrict__ t3, float* __restrict__ stats3) {
  __shared__ float lds[8320 + 4096];
  float* __restrict__ As = lds;          // [128][65]
  float* __restrict__ Ws = lds + 8320;   // [64][64]
  const int row0 = blockIdx.x * 128;
  const int tid  = threadIdx.x;
  const int tx = tid & 7, ty = tid >> 3;

  float acc[4][8];
#pragma unroll
  for (int i = 0; i < 4; ++i)
#pragma unroll
    for (int j = 0; j < 8; ++j) acc[i][j] = 0.f;

  for (int kc = 0; kc < HID; kc += 64) {
    {  // stage A with bn2+relu6 fused
      const int k4 = (tid & 15) * 4;
      const int mb = tid >> 4;
      const float4 sc = *reinterpret_cast<const float4*>(scale2 + kc + k4);
      const float4 sh = *reinterpret_cast<const float4*>(shift2 + kc + k4);
#pragma unroll
      for (int it = 0; it < 8; ++it) {
        const int m = mb + it * 16;
        const int r = row0 + m;
        float4 o = make_float4(0.f, 0.f, 0.f, 0.f);
        if (r < NS) {
          const float4 v = ld4(out2 + (size_t)r * HID + kc + k4);
          o.x = relu6f(fmaf(v.x, sc.x, sh.x));
          o.y = relu6f(fmaf(v.y, sc.y, sh.y));
          o.z = relu6f(fmaf(v.z, sc.z, sh.z));
          o.w = relu6f(fmaf(v.w, sc.w, sh.w));
        }
        float* p = As + m * 65 + k4;
        p[0] = o.x; p[1] = o.y; p[2] = o.z; p[3] = o.w;
      }
    }
    {  // stage W3 chunk [64][64]
      const int n4 = (tid & 15) * 4;
      const int kb = tid >> 4;
#pragma unroll
      for (int it = 0; it < 4; ++it) {
        const int k = kb + it * 16;
        *reinterpret_cast<float4*>(Ws + k * 64 + n4) =
            *reinterpret_cast<const float4*>(w3 + (size_t)(kc + k) * COUT + n4);
      }
    }
    __syncthreads();

#pragma unroll 8
    for (int k = 0; k < 64; ++k) {
      float a[4], b[8];
#pragma unroll
      for (int i = 0; i < 4; ++i) a[i] = As[(ty * 4 + i) * 65 + k];
      float4 b0 = *reinterpret_cast<const float4*>(Ws + k * 64 + tx * 4);
      float4 b1 = *reinterpret_cast<const float4*>(Ws + k * 64 + 32 + tx * 4);
      b[0]=b0.x; b[1]=b0.y; b[2]=b0.z; b[3]=b0.w;
      b[4]=b1.x; b[5]=b1.y; b[6]=b1.z; b[7]=b1.w;
#pragma unroll
      for (int i = 0; i < 4; ++i)
#pragma unroll
        for (int j = 0; j < 8; ++j) acc[i][j] = fmaf(a[i], b[j], acc[i][j]);
    }
    __syncthreads();
  }

#pragma unroll
  for (int i = 0; i < 4; ++i) {
    const int r = row0 + ty * 4 + i;
    if (r < NS) {
      *reinterpret_cast<float4*>(t3 + (size_t)r * COUT + tx * 4) =
          make_float4(acc[i][0], acc[i][1], acc[i][2], acc[i][3]);
      *reinterpret_cast<float4*>(t3 + (size_t)r * COUT + 32 + tx * 4) =
          make_float4(acc[i][4], acc[i][5], acc[i][6], acc[i][7]);
    }
  }

  float cs[8], cq[8];
#pragma unroll
  for (int j = 0; j < 8; ++j) {
    cs[j] = 0.f; cq[j] = 0.f;
#pragma unroll
    for (int i = 0; i < 4; ++i) { float v = acc[i][j]; cs[j] += v; cq[j] += v * v; }
  }
  __syncthreads();
  float* red = lds;  // [32][128]
#pragma unroll
  for (int j = 0; j < 8; ++j) {
    const int col = (j < 4) ? (tx * 4 + j) : (32 + tx * 4 + j - 4);
    red[ty * 128 + col * 2]     = cs[j];
    red[ty * 128 + col * 2 + 1] = cq[j];
  }
  __syncthreads();
  if (tid < 128) {
    float s = 0.f;
#pragma unroll
    for (int t = 0; t < 32; ++t) s += red[t * 128 + tid];
    const int col = tid >> 1, st = tid & 1;
    atomicAdd(stats3 + st * COUT + col, s);
  }
}

// ---------------------------------------------------------------------------
// Tier F (tiny workspace): recompute h1 = relu6(bn1(x@w1)) on the fly.
// W1 cached in LDS as bf16 (48 KB). Block = 384 threads (thread == channel).
// ---------------------------------------------------------------------------
__global__ __launch_bounds__(384)
void k_dw_stats_recomp(const float* __restrict__ x, const float* __restrict__ w1,
                       const int* __restrict__ nidx, const uint8_t* __restrict__ cmask,
                       const float* __restrict__ w2,
                       const float* __restrict__ scale1, const float* __restrict__ shift1,
                       float* __restrict__ stats2) {
  __shared__ u16   W1s[64 * 384];
  __shared__ float xb[KV][64];
  const int c = threadIdx.x;
#pragma unroll
  for (int it = 0; it < 16; ++it) {  // 6144 float4 total
    const int idx4 = it * 384 + c;
    float4 v = *reinterpret_cast<const float4*>(w1 + idx4 * 4);
    ushort4 u; u.x = f2bf(v.x); u.y = f2bf(v.y); u.z = f2bf(v.z); u.w = f2bf(v.w);
    *reinterpret_cast<ushort4*>(W1s + idx4 * 4) = u;
  }
  const float s1 = scale1[c], b1 = shift1[c];
  float w2r[KV];
#pragma unroll
  for (int k = 0; k < KV; ++k) w2r[k] = w2[k * HID + c];

  const int rowBase = blockIdx.x * 64;
  float sum = 0.f, sq = 0.f;
  for (int r = 0; r < 64; ++r) {
    const int i = rowBase + r;
    __syncthreads();
    if (c < 144) {  // 9 rows x 16 float4
      const int k = c >> 4, q = c & 15;
      const int j = nidx[(size_t)i * KV + k];
      *reinterpret_cast<float4*>(&xb[k][q * 4]) =
          *reinterpret_cast<const float4*>(x + (size_t)j * CIN + q * 4);
    }
    __syncthreads();
    const uint8_t* mp = cmask + (size_t)i * KV;
    float acc = 0.f;
#pragma unroll
    for (int k = 0; k < KV; ++k) {
      if (mp[k]) {
        float t = 0.f;
#pragma unroll
        for (int kk = 0; kk < 64; ++kk)
          t = fmaf(xb[k][kk], bf2f(W1s[kk * 384 + c]), t);
        acc = fmaf(relu6f(fmaf(t, s1, b1)), w2r[k], acc);
      }
    }
    sum += acc; sq += acc * acc;
  }
  atomicAdd(stats2 + c,       sum);
  atomicAdd(stats2 + HID + c, sq);
}

__global__ __launch_bounds__(384)
void k_gemm3_recomp(const float* __restrict__ x, const float* __restrict__ w1,
                    const int* __restrict__ nidx, const uint8_t* __restrict__ cmask,
                    const float* __restrict__ w2, const float* __restrict__ w3,
                    const float* __restrict__ scale1, const float* __restrict__ shift1,
                    const float* __restrict__ scale2, const float* __restrict__ shift2,
                    float* __restrict__ out, float* __restrict__ stats3) {
  __shared__ u16   W1s[64 * 384];
  __shared__ float xb[KV][64];
  __shared__ float h2[HID];
  __shared__ float part[6][64];
  const int c = threadIdx.x;
#pragma unroll
  for (int it = 0; it < 16; ++it) {
    const int idx4 = it * 384 + c;
    float4 v = *reinterpret_cast<const float4*>(w1 + idx4 * 4);
    ushort4 u; u.x = f2bf(v.x); u.y = f2bf(v.y); u.z = f2bf(v.z); u.w = f2bf(v.w);
    *reinterpret_cast<ushort4*>(W1s + idx4 * 4) = u;
  }
  const float s1 = scale1[c], b1 = shift1[c];
  const float s2 = scale2[c], b2 = shift2[c];
  float w2r[KV];
#pragma unroll
  for (int k = 0; k < KV; ++k) w2r[k] = w2[k * HID + c];
  const int wv = c >> 6;   // 0..5
  const int ln = c & 63;
  float ssum = 0.f, ssq = 0.f;

  const int rowBase = blockIdx.x * 32;
  for (int r = 0; r < 32; ++r) {
    const int i = rowBase + r;
    __syncthreads();
    if (c < 144) {
      const int k = c >> 4, q = c & 15;
      const int j = nidx[(size_t)i * KV + k];
      *reinterpret_cast<float4*>(&xb[k][q * 4]) =
          *reinterpret_cast<const float4*>(x + (size_t)j * CIN + q * 4);
    }
    __syncthreads();
    const uint8_t* mp = cmask + (size_t)i * KV;
    float acc = 0.f;
#pragma unroll
    for (int k = 0; k < KV; ++k) {
      if (mp[k]) {
        float t = 0.f;
#pragma unroll
        for (int kk = 0; kk < 64; ++kk)
          t = fmaf(xb[k][kk], bf2f(W1s[kk * 384 + c]), t);
        acc = fmaf(relu6f(fmaf(t, s1, b1)), w2r[k], acc);
      }
    }
    h2[c] = relu6f(fmaf(acc, s2, b2));
    __syncthreads();
    float pt = 0.f;
#pragma unroll
    for (int cc = 0; cc < 64; ++cc) {
      const int ch = wv * 64 + cc;
      pt = fmaf(h2[ch], w3[ch * COUT + ln], pt);
    }
    part[wv][ln] = pt;
    __syncthreads();
    if (c < 64) {
      const float t3 = part[0][c] + part[1][c] + part[2][c] +
                       part[3][c] + part[4][c] + part[5][c];
      out[(size_t)i * COUT + c] = t3;
      ssum += t3; ssq += t3 * t3;
    }
  }
  if (c < 64) {
    atomicAdd(stats3 + c,        ssum);
    atomicAdd(stats3 + COUT + c, ssq);
  }
}

// ---------------------------------------------------------------------------
__global__ void k_finalize(const float* __restrict__ gamma, const float* __restrict__ beta,
                           float* __restrict__ stats, int C, float invN) {
  const int c = blockIdx.x * blockDim.x + threadIdx.x;
  if (c >= C) return;
  const float mean = stats[c] * invN;
  const float var  = stats[C + c] * invN - mean * mean;
  const float sc   = gamma[c] / sqrtf(var + BN_EPS);
  stats[2 * C + c] = sc;
  stats[3 * C + c] = fmaf(-mean, sc, beta[c]);
}

// out = bn3(out) + x   (in place on d_out)
__global__ __launch_bounds__(256)
void k_final(const float* __restrict__ x, const float* __restrict__ st3,
             float* __restrict__ out) {
  const int t  = blockIdx.x * 256 + threadIdx.x;
  const int cg = (t & 15) * 4;
  const float4 v  = *reinterpret_cast<const float4*>(out + (size_t)t * 4);
  const float4 xi = *reinterpret_cast<const float4*>(x  + (size_t)t * 4);
  const float4 sc = *reinterpret_cast<const float4*>(st3 + 128 + cg);
  const float4 sh = *reinterpret_cast<const float4*>(st3 + 192 + cg);
  float4 o;
  o.x = fmaf(v.x, sc.x, sh.x) + xi.x;
  o.y = fmaf(v.y, sc.y, sh.y) + xi.y;
  o.z = fmaf(v.z, sc.z, sh.z) + xi.z;
  o.w = fmaf(v.w, sc.w, sh.w) + xi.w;
  *reinterpret_cast<float4*>(out + (size_t)t * 4) = o;
}

// ---------------------------------------------------------------------------
extern "C" void kernel_launch(void* const* d_in, const int* in_sizes, int n_in,
                              void* d_out, int out_size, void* d_ws, size_t ws_size,
                              hipStream_t stream) {
  const float* x    = (const float*)d_in[0];
  const float* w1   = (const float*)d_in[1];
  const float* g1   = (const float*)d_in[2];
  const float* b1   = (const float*)d_in[3];
  const float* w2   = (const float*)d_in[4];
  const float* g2   = (const float*)d_in[5];
  const float* b2   = (const float*)d_in[6];
  const float* w3   = (const float*)d_in[7];
  const float* g3   = (const float*)d_in[8];
  const float* b3   = (const float*)d_in[9];
  const int*   nidx = (const int*)d_in[10];
  const void*  mraw = d_in[11];
  float* out = (float*)d_out;

  const size_t NH   = (size_t)NS * HID;            // 76.8M elements
  const size_t BASE = (size_t)2 * 1024 * 1024;     // stats + flag + cmask
  const size_t need_C = BASE + NH * 4;             // bf16 t1 + bf16 out2 (~309 MB)
  const size_t need_F = BASE;                      // recompute tier (~2 MB)

  char* p = (char*)d_ws;
  float*   st    = (float*)p;                  // 3328 floats: stats1/2/3
  int*     flag  = (int*)(p + 13312);
  uint8_t* cmask = (uint8_t*)(p + 16384);      // 1.8 MB
  float* stats1 = st;          // sum[384],sq[384],scale[384],shift[384]
  float* stats2 = st + 1536;
  float* stats3 = st + 3072;
  const float invN = 1.0f / (float)NS;
  const int NKV = NS * KV;

  if (ws_size < need_F) {  // cannot even canonicalize: graceful diagnostic
    hipMemcpyAsync(d_out, d_in[0], (size_t)out_size * sizeof(float),
                   hipMemcpyDeviceToDevice, stream);
    return;
  }

  hipMemsetAsync(st, 0, 13312, stream);
  k_detect<<<1, 256, 0, stream>>>((const uint8_t*)mraw, flag);
  k_canon<<<(NKV + 255) / 256, 256, 0, stream>>>(mraw, flag, cmask, NKV);

  if (ws_size >= need_C) {
    // ---- bf16/bf16 materialized tier ----
    u16* t1   = (u16*)(p + BASE);
    u16* out2 = (u16*)(p + BASE + NH * 2);
    dim3 gA((NS + 127) / 128, HID / 128);
    k_gemm1<u16, true><<<gA, 256, 0, stream>>>(x, w1, t1, stats1);
    k_finalize<<<1, HID, 0, stream>>>(g1, b1, stats1, HID, invN);
    k_dwconv<u16, u16><<<NS / 64, HID, 0, stream>>>(t1, nidx, cmask, w2,
                                                    stats1 + 768, stats1 + 1152,
                                                    out2, stats2);
    k_finalize<<<1, HID, 0, stream>>>(g2, b2, stats2, HID, invN);
    k_gemm3<u16><<<(NS + 127) / 128, 256, 0, stream>>>(out2, w3,
                                                       stats2 + 768, stats2 + 1152,
                                                       out, stats3);
    k_finalize<<<1, COUT, 0, stream>>>(g3, b3, stats3, COUT, invN);
    k_final<<<(NS * COUT / 4) / 256, 256, 0, stream>>>(x, stats3, out);
  } else {
    // ---- tiny-workspace recompute tier ----
    dim3 gA((NS + 127) / 128, HID / 128);
    k_gemm1<float, false><<<gA, 256, 0, stream>>>(x, w1, (float*)nullptr, stats1);
    k_finalize<<<1, HID, 0, stream>>>(g1, b1, stats1, HID, invN);
    k_dw_stats_recomp<<<NS / 64, HID, 0, stream>>>(x, w1, nidx, cmask, w2,
                                                   stats1 + 768, stats1 + 1152, stats2);
    k_finalize<<<1, HID, 0, stream>>>(g2, b2, stats2, HID, invN);
    k_gemm3_recomp<<<NS / 32, HID, 0, stream>>>(x, w1, nidx, cmask, w2, w3,
                                                stats1 + 768, stats1 + 1152,
                                                stats2 + 768, stats2 + 1152,
                                                out, stats3);
    k_finalize<<<1, COUT, 0, stream>>>(g3, b3, stats3, COUT, invN);
    k_final<<<(NS * COUT / 4) / 256, 256, 0, stream>>>(x, stats3, out);
  }
}

// Round 6
// 2248.171 us; speedup vs baseline: 3.9892x; 3.9892x over previous
//
#include <hip/hip_runtime.h>
#include <cstdint>
#include <cstddef>

#define NS   200000
#define CIN  64
#define HID  384
#define COUT 64
#define KV   9
#define BN_EPS 1e-5f

typedef unsigned short u16;  // bf16 bits

__device__ __forceinline__ float relu6f(float v) { return fminf(fmaxf(v, 0.f), 6.f); }

__device__ __forceinline__ float bf2f(u16 u) {
  union { unsigned int i; float f; } c; c.i = ((unsigned int)u) << 16; return c.f;
}
__device__ __forceinline__ u16 f2bf(float f) {
  union { float f; unsigned int i; } c; c.f = f;
  unsigned int x = c.i;
  return (u16)((x + 0x7FFFu + ((x >> 16) & 1u)) >> 16);  // RNE
}

// ---- storage-type polymorphic load/store ----
__device__ __forceinline__ float4 ld4(const float* p) { return *reinterpret_cast<const float4*>(p); }
__device__ __forceinline__ float4 ld4(const u16* p) {
  ushort4 u = *reinterpret_cast<const ushort4*>(p);
  return make_float4(bf2f(u.x), bf2f(u.y), bf2f(u.z), bf2f(u.w));
}
__device__ __forceinline__ void st4(float* p, float4 v) { *reinterpret_cast<float4*>(p) = v; }
__device__ __forceinline__ void st4(u16* p, float4 v) {
  ushort4 u; u.x = f2bf(v.x); u.y = f2bf(v.y); u.z = f2bf(v.z); u.w = f2bf(v.w);
  *reinterpret_cast<ushort4*>(p) = u;
}
// uint8 store: input already in [0,6] (relu6 applied) -> quantize step 6/255
__device__ __forceinline__ void st4(uint8_t* p, float4 v) {
  uchar4 u;
  u.x = (uint8_t)(v.x * 42.5f + 0.5f);
  u.y = (uint8_t)(v.y * 42.5f + 0.5f);
  u.z = (uint8_t)(v.z * 42.5f + 0.5f);
  u.w = (uint8_t)(v.w * 42.5f + 0.5f);
  *reinterpret_cast<uchar4*>(p) = u;
}
__device__ __forceinline__ float ld1(const float* p) { return *p; }
__device__ __forceinline__ float ld1(const u16* p) { return bf2f(*p); }
__device__ __forceinline__ void st1(float* p, float v) { *p = v; }
__device__ __forceinline__ void st1(u16* p, float v) { *p = f2bf(v); }

#define U8DQ 0.023529412f  // 6/255

// gather-activation loaders: bf16 raw (apply bn1+relu6) vs u8 pre-activated
__device__ __forceinline__ float4 load_h4(const u16* p, float4 s1, float4 b1) {
  ushort4 v = *reinterpret_cast<const ushort4*>(p);
  return make_float4(relu6f(fmaf(bf2f(v.x), s1.x, b1.x)),
                     relu6f(fmaf(bf2f(v.y), s1.y, b1.y)),
                     relu6f(fmaf(bf2f(v.z), s1.z, b1.z)),
                     relu6f(fmaf(bf2f(v.w), s1.w, b1.w)));
}
__device__ __forceinline__ float4 load_h4(const uint8_t* p, float4, float4) {
  uchar4 v = *reinterpret_cast<const uchar4*>(p);
  return make_float4(v.x * U8DQ, v.y * U8DQ, v.z * U8DQ, v.w * U8DQ);
}
__device__ __forceinline__ float2 load_h2(const u16* p, float2 s1, float2 b1) {
  ushort2 v = *reinterpret_cast<const ushort2*>(p);
  return make_float2(relu6f(fmaf(bf2f(v.x), s1.x, b1.x)),
                     relu6f(fmaf(bf2f(v.y), s1.y, b1.y)));
}
__device__ __forceinline__ float2 load_h2(const uint8_t* p, float2, float2) {
  uchar2 v = *reinterpret_cast<const uchar2*>(p);
  return make_float2(v.x * U8DQ, v.y * U8DQ);
}

// ---------------------------------------------------------------------------
// Mask layout detection + canonicalization to uint8 (proven in R4).
// ---------------------------------------------------------------------------
__global__ void k_detect(const uint8_t* __restrict__ raw, int* __restrict__ flag) {
  __shared__ int nz[4];
  if (threadIdx.x < 4) nz[threadIdx.x] = 0;
  __syncthreads();
  int cnt[4] = {0, 0, 0, 0};
  const uint8_t* p = raw + threadIdx.x * 16;
#pragma unroll
  for (int j = 0; j < 16; ++j) if (p[j]) cnt[j & 3]++;
#pragma unroll
  for (int r = 0; r < 4; ++r) if (cnt[r]) atomicAdd(&nz[r], cnt[r]);
  __syncthreads();
  if (threadIdx.x == 0) {
    int f;
    if (nz[1] == 0 && nz[2] == 0 && nz[3] == 0) f = 0;       // int32
    else if (nz[0] == 0 && nz[1] == 0)          f = 2;       // float32
    else                                        f = 1;       // uint8
    *flag = f;
  }
}

__global__ __launch_bounds__(256)
void k_canon(const void* __restrict__ raw, const int* __restrict__ flag,
             uint8_t* __restrict__ cmask, int n) {
  const int e = blockIdx.x * 256 + threadIdx.x;
  if (e >= n) return;
  const int f = *flag;
  uint8_t v;
  if (f == 0)      v = ((const int*)raw)[e] != 0;
  else if (f == 1) v = ((const uint8_t*)raw)[e] != 0;
  else             v = ((const float*)raw)[e] != 0.f;
  cmask[e] = v;
}

// ---------------------------------------------------------------------------
// Kernel A: t1 = x @ w1 [NS x HID]. STORE: write t1 (raw, or ACT: bn1+relu6
// applied, e.g. uint8). Stats accumulated only when !ACT.
// Tile 128x128, K=64. 256 threads, 8x8 register blocking.
// ---------------------------------------------------------------------------
template <typename TO, bool STORE, bool ACT>
__global__ __launch_bounds__(256, 2)
void k_gemm1(const float* __restrict__ x, const float* __restrict__ w1,
             TO* __restrict__ t1, float* __restrict__ stats1,
             const float* __restrict__ sc1, const float* __restrict__ sh1) {
  __shared__ float lds[8320 + 8192];
  float* __restrict__ Xs = lds;          // [128][65]
  float* __restrict__ Ws = lds + 8320;   // [64][128]
  const int row0 = blockIdx.x * 128;
  const int col0 = blockIdx.y * 128;
  const int tid  = threadIdx.x;

  {  // stage X tile [m][k], stride 65
    const int k4 = (tid & 15) * 4;
    const int mb = tid >> 4;
#pragma unroll
    for (int it = 0; it < 8; ++it) {
      const int m = mb + it * 16;
      const int r = row0 + m;
      float4 v = make_float4(0.f, 0.f, 0.f, 0.f);
      if (r < NS) v = *reinterpret_cast<const float4*>(x + (size_t)r * CIN + k4);
      float* p = Xs + m * 65 + k4;
      p[0] = v.x; p[1] = v.y; p[2] = v.z; p[3] = v.w;
    }
  }
  {  // stage W tile [k][n]
    const int n4 = (tid & 31) * 4;
    const int kb = tid >> 5;
#pragma unroll
    for (int it = 0; it < 8; ++it) {
      const int k = kb + it * 8;
      *reinterpret_cast<float4*>(Ws + k * 128 + n4) =
          *reinterpret_cast<const float4*>(w1 + k * HID + col0 + n4);
    }
  }
  __syncthreads();

  const int tx = tid & 15, ty = tid >> 4;
  float acc[8][8];
#pragma unroll
  for (int i = 0; i < 8; ++i)
#pragma unroll
    for (int j = 0; j < 8; ++j) acc[i][j] = 0.f;

#pragma unroll 8
  for (int k = 0; k < 64; ++k) {
    float a[8], b[8];
#pragma unroll
    for (int i = 0; i < 4; ++i) {
      a[i]     = Xs[(ty * 4 + i) * 65 + k];
      a[4 + i] = Xs[(64 + ty * 4 + i) * 65 + k];
    }
    float4 b0 = *reinterpret_cast<const float4*>(Ws + k * 128 + tx * 4);
    float4 b1 = *reinterpret_cast<const float4*>(Ws + k * 128 + 64 + tx * 4);
    b[0]=b0.x; b[1]=b0.y; b[2]=b0.z; b[3]=b0.w;
    b[4]=b1.x; b[5]=b1.y; b[6]=b1.z; b[7]=b1.w;
#pragma unroll
    for (int i = 0; i < 8; ++i)
#pragma unroll
      for (int j = 0; j < 8; ++j) acc[i][j] = fmaf(a[i], b[j], acc[i][j]);
  }

  if constexpr (STORE) {
    float4 sA = make_float4(1,1,1,1), bA = make_float4(0,0,0,0);
    float4 sB = sA, bB = bA;
    if constexpr (ACT) {
      sA = *reinterpret_cast<const float4*>(sc1 + col0 + tx * 4);
      bA = *reinterpret_cast<const float4*>(sh1 + col0 + tx * 4);
      sB = *reinterpret_cast<const float4*>(sc1 + col0 + 64 + tx * 4);
      bB = *reinterpret_cast<const float4*>(sh1 + col0 + 64 + tx * 4);
    }
#pragma unroll
    for (int i = 0; i < 8; ++i) {
      const int r = row0 + ((i < 4) ? (ty * 4 + i) : (64 + ty * 4 + i - 4));
      if (r < NS) {
        float4 v0 = make_float4(acc[i][0], acc[i][1], acc[i][2], acc[i][3]);
        float4 v1 = make_float4(acc[i][4], acc[i][5], acc[i][6], acc[i][7]);
        if constexpr (ACT) {
          v0.x = relu6f(fmaf(v0.x, sA.x, bA.x)); v0.y = relu6f(fmaf(v0.y, sA.y, bA.y));
          v0.z = relu6f(fmaf(v0.z, sA.z, bA.z)); v0.w = relu6f(fmaf(v0.w, sA.w, bA.w));
          v1.x = relu6f(fmaf(v1.x, sB.x, bB.x)); v1.y = relu6f(fmaf(v1.y, sB.y, bB.y));
          v1.z = relu6f(fmaf(v1.z, sB.z, bB.z)); v1.w = relu6f(fmaf(v1.w, sB.w, bB.w));
        }
        st4(t1 + (size_t)r * HID + col0 + tx * 4, v0);
        st4(t1 + (size_t)r * HID + col0 + 64 + tx * 4, v1);
      }
    }
  }

  if constexpr (!ACT) {
    float cs[8], cq[8];
#pragma unroll
    for (int j = 0; j < 8; ++j) {
      cs[j] = 0.f; cq[j] = 0.f;
#pragma unroll
      for (int i = 0; i < 8; ++i) { float v = acc[i][j]; cs[j] += v; cq[j] += v * v; }
    }
    __syncthreads();
    float* red = lds;  // [16][256]
#pragma unroll
    for (int j = 0; j < 8; ++j) {
      const int col = (j < 4) ? (tx * 4 + j) : (64 + tx * 4 + j - 4);
      red[ty * 256 + col * 2]     = cs[j];
      red[ty * 256 + col * 2 + 1] = cq[j];
    }
    __syncthreads();
    {
      float s = 0.f;
#pragma unroll
      for (int t = 0; t < 16; ++t) s += red[t * 256 + tid];
      const int col = tid >> 1, st = tid & 1;
      atomicAdd(stats1 + st * HID + col0 + col, s);
    }
  }
}

// ---------------------------------------------------------------------------
// Gather stats pass: out2 computed on the fly (NOT stored) -> BN2 sum/sumsq.
// 384 threads = 2 rows x 192 lanes (2 channels each). 64 rows per block.
// Identical fp32 fma order as k_gemm3f staging -> BN2 stats exactly consistent.
// ---------------------------------------------------------------------------
template <typename T>
__global__ __launch_bounds__(384)
void k_dw_stats(const T* __restrict__ h1, const int* __restrict__ nidx,
                const uint8_t* __restrict__ cmask, const float* __restrict__ w2,
                const float* __restrict__ scale1, const float* __restrict__ shift1,
                float* __restrict__ stats2) {
  const int tid  = threadIdx.x;
  const int half = (tid >= 192) ? 1 : 0;
  const int c0   = (tid - half * 192) * 2;
  const float2 s1 = *reinterpret_cast<const float2*>(scale1 + c0);
  const float2 b1 = *reinterpret_cast<const float2*>(shift1 + c0);
  float w2a[KV], w2b[KV];
#pragma unroll
  for (int k = 0; k < KV; ++k) {
    float2 w = *reinterpret_cast<const float2*>(w2 + k * HID + c0);
    w2a[k] = w.x; w2b[k] = w.y;
  }
  const int rowBase = blockIdx.x * 64;
  float sum0 = 0.f, sum1 = 0.f, sq0 = 0.f, sq1 = 0.f;
  for (int r = 0; r < 64; r += 2) {
    const int i = rowBase + r + half;
    const int*     ip = nidx  + (size_t)i * KV;
    const uint8_t* mp = cmask + (size_t)i * KV;
    float a0 = 0.f, a1 = 0.f;
#pragma unroll
    for (int k = 0; k < KV; ++k) {
      if (mp[k]) {
        const int j = ip[k];
        float2 h = load_h2(h1 + (size_t)j * HID + c0, s1, b1);
        a0 = fmaf(h.x, w2a[k], a0);
        a1 = fmaf(h.y, w2b[k], a1);
      }
    }
    sum0 += a0; sq0 += a0 * a0;
    sum1 += a1; sq1 += a1 * a1;
  }
  atomicAdd(stats2 + c0,           sum0);
  atomicAdd(stats2 + c0 + 1,       sum1);
  atomicAdd(stats2 + HID + c0,     sq0);
  atomicAdd(stats2 + HID + c0 + 1, sq1);
}

// ---------------------------------------------------------------------------
// Fused gemm3: A-tile staged by RECOMPUTING out2 rows (gather from L3-resident
// h1/t1), then bn2+relu6, then GEMM with w3 -> d_out + BN3 stats.
// Tile 128x64, K chunked by 64. 256 threads, 4x8 blocking.
// ---------------------------------------------------------------------------
template <typename T>
__global__ __launch_bounds__(256, 2)
void k_gemm3f(const T* __restrict__ h1, const int* __restrict__ nidx,
              const uint8_t* __restrict__ cmask, const float* __restrict__ w2,
              const float* __restrict__ w3,
              const float* __restrict__ sc1v, const float* __restrict__ sh1v,
              const float* __restrict__ sc2v, const float* __restrict__ sh2v,
              float* __restrict__ out, float* __restrict__ stats3) {
  __shared__ float lds[8320 + 4096 + 576];
  float* __restrict__ As  = lds;                 // [128][65]
  float* __restrict__ Ws  = lds + 8320;          // [64][64]
  float* __restrict__ W2s = lds + 8320 + 4096;   // [9][64]
  const int row0 = blockIdx.x * 128;
  const int tid  = threadIdx.x;
  const int tx = tid & 7, ty = tid >> 3;

  float acc[4][8];
#pragma unroll
  for (int i = 0; i < 4; ++i)
#pragma unroll
    for (int j = 0; j < 8; ++j) acc[i][j] = 0.f;

  for (int kc = 0; kc < HID; kc += 64) {
    // stage w2 chunk [9][64]
    if (tid < 144) {
      const int k = tid / 16, q4 = (tid & 15) * 4;
      *reinterpret_cast<float4*>(W2s + k * 64 + q4) =
          *reinterpret_cast<const float4*>(w2 + k * HID + kc + q4);
    }
    __syncthreads();

    {  // stage A: recompute out2 rows via gather, apply bn2+relu6
      const int k4 = (tid & 15) * 4;
      const int mb = tid >> 4;
      const float4 s1 = *reinterpret_cast<const float4*>(sc1v + kc + k4);
      const float4 b1 = *reinterpret_cast<const float4*>(sh1v + kc + k4);
      const float4 s2 = *reinterpret_cast<const float4*>(sc2v + kc + k4);
      const float4 b2 = *reinterpret_cast<const float4*>(sh2v + kc + k4);
#pragma unroll
      for (int it = 0; it < 8; ++it) {
        const int m = mb + it * 16;
        const int i = row0 + m;
        float4 o = make_float4(0.f, 0.f, 0.f, 0.f);
        if (i < NS) {
          const int*     ip = nidx  + (size_t)i * KV;
          const uint8_t* mp = cmask + (size_t)i * KV;
          float4 a = make_float4(0.f, 0.f, 0.f, 0.f);
#pragma unroll
          for (int k = 0; k < KV; ++k) {
            if (mp[k]) {
              const int j = ip[k];
              float4 h = load_h4(h1 + (size_t)j * HID + kc + k4, s1, b1);
              a.x = fmaf(h.x, W2s[k * 64 + k4],     a.x);
              a.y = fmaf(h.y, W2s[k * 64 + k4 + 1], a.y);
              a.z = fmaf(h.z, W2s[k * 64 + k4 + 2], a.z);
              a.w = fmaf(h.w, W2s[k * 64 + k4 + 3], a.w);
            }
          }
          o.x = relu6f(fmaf(a.x, s2.x, b2.x));
          o.y = relu6f(fmaf(a.y, s2.y, b2.y));
          o.z = relu6f(fmaf(a.z, s2.z, b2.z));
          o.w = relu6f(fmaf(a.w, s2.w, b2.w));
        }
        float* p = As + m * 65 + k4;
        p[0] = o.x; p[1] = o.y; p[2] = o.z; p[3] = o.w;
      }
    }
    {  // stage W3 chunk [64][64]
      const int n4 = (tid & 15) * 4;
      const int kb = tid >> 4;
#pragma unroll
      for (int it = 0; it < 4; ++it) {
        const int k = kb + it * 16;
        *reinterpret_cast<float4*>(Ws + k * 64 + n4) =
            *reinterpret_cast<const float4*>(w3 + (size_t)(kc + k) * COUT + n4);
      }
    }
    __syncthreads();

#pragma unroll 8
    for (int k = 0; k < 64; ++k) {
      float a[4], b[8];
#pragma unroll
      for (int i = 0; i < 4; ++i) a[i] = As[(ty * 4 + i) * 65 + k];
      float4 b0 = *reinterpret_cast<const float4*>(Ws + k * 64 + tx * 4);
      float4 b1 = *reinterpret_cast<const float4*>(Ws + k * 64 + 32 + tx * 4);
      b[0]=b0.x; b[1]=b0.y; b[2]=b0.z; b[3]=b0.w;
      b[4]=b1.x; b[5]=b1.y; b[6]=b1.z; b[7]=b1.w;
#pragma unroll
      for (int i = 0; i < 4; ++i)
#pragma unroll
        for (int j = 0; j < 8; ++j) acc[i][j] = fmaf(a[i], b[j], acc[i][j]);
    }
    __syncthreads();
  }

#pragma unroll
  for (int i = 0; i < 4; ++i) {
    const int r = row0 + ty * 4 + i;
    if (r < NS) {
      *reinterpret_cast<float4*>(out + (size_t)r * COUT + tx * 4) =
          make_float4(acc[i][0], acc[i][1], acc[i][2], acc[i][3]);
      *reinterpret_cast<float4*>(out + (size_t)r * COUT + 32 + tx * 4) =
          make_float4(acc[i][4], acc[i][5], acc[i][6], acc[i][7]);
    }
  }

  float cs[8], cq[8];
#pragma unroll
  for (int j = 0; j < 8; ++j) {
    cs[j] = 0.f; cq[j] = 0.f;
#pragma unroll
    for (int i = 0; i < 4; ++i) { float v = acc[i][j]; cs[j] += v; cq[j] += v * v; }
  }
  __syncthreads();
  float* red = lds;  // [32][128]
#pragma unroll
  for (int j = 0; j < 8; ++j) {
    const int col = (j < 4) ? (tx * 4 + j) : (32 + tx * 4 + j - 4);
    red[ty * 128 + col * 2]     = cs[j];
    red[ty * 128 + col * 2 + 1] = cq[j];
  }
  __syncthreads();
  if (tid < 128) {
    float s = 0.f;
#pragma unroll
    for (int t = 0; t < 32; ++t) s += red[t * 128 + tid];
    const int col = tid >> 1, st = tid & 1;
    atomicAdd(stats3 + st * COUT + col, s);
  }
}

// ---------------------------------------------------------------------------
// Tier A kernels (materialized out2) — kept for large-ws case.
// ---------------------------------------------------------------------------
template <typename TI, typename TO>
__global__ __launch_bounds__(384)
void k_dwconv(const TI* __restrict__ t1, const int* __restrict__ nidx,
              const uint8_t* __restrict__ cmask, const float* __restrict__ w2,
              const float* __restrict__ scale1, const float* __restrict__ shift1,
              TO* __restrict__ out2, float* __restrict__ stats2) {
  const int c  = threadIdx.x;
  const float s1 = scale1[c];
  const float b1 = shift1[c];
  float w2r[KV];
#pragma unroll
  for (int k = 0; k < KV; ++k) w2r[k] = w2[k * HID + c];
  const int rowBase = blockIdx.x * 64;
  float sum = 0.f, sq = 0.f;
  for (int r = 0; r < 64; ++r) {
    const int i = rowBase + r;
    const int*     ip = nidx  + (size_t)i * KV;
    const uint8_t* mp = cmask + (size_t)i * KV;
    float acc = 0.f;
#pragma unroll
    for (int k = 0; k < KV; ++k) {
      if (mp[k]) {
        const int j = ip[k];
        const float v = ld1(t1 + (size_t)j * HID + c);
        const float h = relu6f(fmaf(v, s1, b1));
        acc = fmaf(h, w2r[k], acc);
      }
    }
    st1(out2 + (size_t)i * HID + c, acc);
    sum += acc; sq += acc * acc;
  }
  atomicAdd(stats2 + c,       sum);
  atomicAdd(stats2 + HID + c, sq);
}

template <typename TI>
__global__ __launch_bounds__(256, 3)
void k_gemm3(const TI* __restrict__ out2, const float* __restrict__ w3,
             const float* __restrict__ scale2, const float* __restrict__ shift2,
             float* __restrict__ t3, float* __restrict__ stats3) {
  __shared__ float lds[8320 + 4096];
  float* __restrict__ As = lds;          // [128][65]
  float* __restrict__ Ws = lds + 8320;   // [64][64]
  const int row0 = blockIdx.x * 128;
  const int tid  = threadIdx.x;
  const int tx = tid & 7, ty = tid >> 3;
  float acc[4][8];
#pragma unroll
  for (int i = 0; i < 4; ++i)
#pragma unroll
    for (int j = 0; j < 8; ++j) acc[i][j] = 0.f;

  for (int kc = 0; kc < HID; kc += 64) {
    {
      const int k4 = (tid & 15) * 4;
      const int mb = tid >> 4;
      const float4 sc = *reinterpret_cast<const float4*>(scale2 + kc + k4);
      const float4 sh = *reinterpret_cast<const float4*>(shift2 + kc + k4);
#pragma unroll
      for (int it = 0; it < 8; ++it) {
        const int m = mb + it * 16;
        const int r = row0 + m;
        float4 o = make_float4(0.f, 0.f, 0.f, 0.f);
        if (r < NS) {
          const float4 v = ld4(out2 + (size_t)r * HID + kc + k4);
          o.x = relu6f(fmaf(v.x, sc.x, sh.x));
          o.y = relu6f(fmaf(v.y, sc.y, sh.y));
          o.z = relu6f(fmaf(v.z, sc.z, sh.z));
          o.w = relu6f(fmaf(v.w, sc.w, sh.w));
        }
        float* p = As + m * 65 + k4;
        p[0] = o.x; p[1] = o.y; p[2] = o.z; p[3] = o.w;
      }
    }
    {
      const int n4 = (tid & 15) * 4;
      const int kb = tid >> 4;
#pragma unroll
      for (int it = 0; it < 4; ++it) {
        const int k = kb + it * 16;
        *reinterpret_cast<float4*>(Ws + k * 64 + n4) =
            *reinterpret_cast<const float4*>(w3 + (size_t)(kc + k) * COUT + n4);
      }
    }
    __syncthreads();
#pragma unroll 8
    for (int k = 0; k < 64; ++k) {
      float a[4], b[8];
#pragma unroll
      for (int i = 0; i < 4; ++i) a[i] = As[(ty * 4 + i) * 65 + k];
      float4 b0 = *reinterpret_cast<const float4*>(Ws + k * 64 + tx * 4);
      float4 b1 = *reinterpret_cast<const float4*>(Ws + k * 64 + 32 + tx * 4);
      b[0]=b0.x; b[1]=b0.y; b[2]=b0.z; b[3]=b0.w;
      b[4]=b1.x; b[5]=b1.y; b[6]=b1.z; b[7]=b1.w;
#pragma unroll
      for (int i = 0; i < 4; ++i)
#pragma unroll
        for (int j = 0; j < 8; ++j) acc[i][j] = fmaf(a[i], b[j], acc[i][j]);
    }
    __syncthreads();
  }
#pragma unroll
  for (int i = 0; i < 4; ++i) {
    const int r = row0 + ty * 4 + i;
    if (r < NS) {
      *reinterpret_cast<float4*>(t3 + (size_t)r * COUT + tx * 4) =
          make_float4(acc[i][0], acc[i][1], acc[i][2], acc[i][3]);
      *reinterpret_cast<float4*>(t3 + (size_t)r * COUT + 32 + tx * 4) =
          make_float4(acc[i][4], acc[i][5], acc[i][6], acc[i][7]);
    }
  }
  float cs[8], cq[8];
#pragma unroll
  for (int j = 0; j < 8; ++j) {
    cs[j] = 0.f; cq[j] = 0.f;
#pragma unroll
    for (int i = 0; i < 4; ++i) { float v = acc[i][j]; cs[j] += v; cq[j] += v * v; }
  }
  __syncthreads();
  float* red = lds;
#pragma unroll
  for (int j = 0; j < 8; ++j) {
    const int col = (j < 4) ? (tx * 4 + j) : (32 + tx * 4 + j - 4);
    red[ty * 128 + col * 2]     = cs[j];
    red[ty * 128 + col * 2 + 1] = cq[j];
  }
  __syncthreads();
  if (tid < 128) {
    float s = 0.f;
#pragma unroll
    for (int t = 0; t < 32; ++t) s += red[t * 128 + tid];
    const int col = tid >> 1, st = tid & 1;
    atomicAdd(stats3 + st * COUT + col, s);
  }
}

// ---------------------------------------------------------------------------
// Tier F (tiny workspace) — unchanged recompute fallback from R4.
// ---------------------------------------------------------------------------
__global__ __launch_bounds__(384)
void k_dw_stats_recomp(const float* __restrict__ x, const float* __restrict__ w1,
                       const int* __restrict__ nidx, const uint8_t* __restrict__ cmask,
                       const float* __restrict__ w2,
                       const float* __restrict__ scale1, const float* __restrict__ shift1,
                       float* __restrict__ stats2) {
  __shared__ u16   W1s[64 * 384];
  __shared__ float xb[KV][64];
  const int c = threadIdx.x;
#pragma unroll
  for (int it = 0; it < 16; ++it) {
    const int idx4 = it * 384 + c;
    float4 v = *reinterpret_cast<const float4*>(w1 + idx4 * 4);
    ushort4 u; u.x = f2bf(v.x); u.y = f2bf(v.y); u.z = f2bf(v.z); u.w = f2bf(v.w);
    *reinterpret_cast<ushort4*>(W1s + idx4 * 4) = u;
  }
  const float s1 = scale1[c], b1 = shift1[c];
  float w2r[KV];
#pragma unroll
  for (int k = 0; k < KV; ++k) w2r[k] = w2[k * HID + c];
  const int rowBase = blockIdx.x * 64;
  float sum = 0.f, sq = 0.f;
  for (int r = 0; r < 64; ++r) {
    const int i = rowBase + r;
    __syncthreads();
    if (c < 144) {
      const int k = c >> 4, q = c & 15;
      const int j = nidx[(size_t)i * KV + k];
      *reinterpret_cast<float4*>(&xb[k][q * 4]) =
          *reinterpret_cast<const float4*>(x + (size_t)j * CIN + q * 4);
    }
    __syncthreads();
    const uint8_t* mp = cmask + (size_t)i * KV;
    float acc = 0.f;
#pragma unroll
    for (int k = 0; k < KV; ++k) {
      if (mp[k]) {
        float t = 0.f;
#pragma unroll
        for (int kk = 0; kk < 64; ++kk)
          t = fmaf(xb[k][kk], bf2f(W1s[kk * 384 + c]), t);
        acc = fmaf(relu6f(fmaf(t, s1, b1)), w2r[k], acc);
      }
    }
    sum += acc; sq += acc * acc;
  }
  atomicAdd(stats2 + c,       sum);
  atomicAdd(stats2 + HID + c, sq);
}

__global__ __launch_bounds__(384)
void k_gemm3_recomp(const float* __restrict__ x, const float* __restrict__ w1,
                    const int* __restrict__ nidx, const uint8_t* __restrict__ cmask,
                    const float* __restrict__ w2, const float* __restrict__ w3,
                    const float* __restrict__ scale1, const float* __restrict__ shift1,
                    const float* __restrict__ scale2, const float* __restrict__ shift2,
                    float* __restrict__ out, float* __restrict__ stats3) {
  __shared__ u16   W1s[64 * 384];
  __shared__ float xb[KV][64];
  __shared__ float h2[HID];
  __shared__ float part[6][64];
  const int c = threadIdx.x;
#pragma unroll
  for (int it = 0; it < 16; ++it) {
    const int idx4 = it * 384 + c;
    float4 v = *reinterpret_cast<const float4*>(w1 + idx4 * 4);
    ushort4 u; u.x = f2bf(v.x); u.y = f2bf(v.y); u.z = f2bf(v.z); u.w = f2bf(v.w);
    *reinterpret_cast<ushort4*>(W1s + idx4 * 4) = u;
  }
  const float s1 = scale1[c], b1 = shift1[c];
  const float s2 = scale2[c], b2 = shift2[c];
  float w2r[KV];
#pragma unroll
  for (int k = 0; k < KV; ++k) w2r[k] = w2[k * HID + c];
  const int wv = c >> 6;
  const int ln = c & 63;
  float ssum = 0.f, ssq = 0.f;
  const int rowBase = blockIdx.x * 32;
  for (int r = 0; r < 32; ++r) {
    const int i = rowBase + r;
    __syncthreads();
    if (c < 144) {
      const int k = c >> 4, q = c & 15;
      const int j = nidx[(size_t)i * KV + k];
      *reinterpret_cast<float4*>(&xb[k][q * 4]) =
          *reinterpret_cast<const float4*>(x + (size_t)j * CIN + q * 4);
    }
    __syncthreads();
    const uint8_t* mp = cmask + (size_t)i * KV;
    float acc = 0.f;
#pragma unroll
    for (int k = 0; k < KV; ++k) {
      if (mp[k]) {
        float t = 0.f;
#pragma unroll
        for (int kk = 0; kk < 64; ++kk)
          t = fmaf(xb[k][kk], bf2f(W1s[kk * 384 + c]), t);
        acc = fmaf(relu6f(fmaf(t, s1, b1)), w2r[k], acc);
      }
    }
    h2[c] = relu6f(fmaf(acc, s2, b2));
    __syncthreads();
    float pt = 0.f;
#pragma unroll
    for (int cc = 0; cc < 64; ++cc) {
      const int ch = wv * 64 + cc;
      pt = fmaf(h2[ch], w3[ch * COUT + ln], pt);
    }
    part[wv][ln] = pt;
    __syncthreads();
    if (c < 64) {
      const float t3 = part[0][c] + part[1][c] + part[2][c] +
                       part[3][c] + part[4][c] + part[5][c];
      out[(size_t)i * COUT + c] = t3;
      ssum += t3; ssq += t3 * t3;
    }
  }
  if (c < 64) {
    atomicAdd(stats3 + c,        ssum);
    atomicAdd(stats3 + COUT + c, ssq);
  }
}

// ---------------------------------------------------------------------------
__global__ void k_finalize(const float* __restrict__ gamma, const float* __restrict__ beta,
                           float* __restrict__ stats, int C, float invN) {
  const int c = blockIdx.x * blockDim.x + threadIdx.x;
  if (c >= C) return;
  const float mean = stats[c] * invN;
  const float var  = stats[C + c] * invN - mean * mean;
  const float sc   = gamma[c] / sqrtf(var + BN_EPS);
  stats[2 * C + c] = sc;
  stats[3 * C + c] = fmaf(-mean, sc, beta[c]);
}

__global__ __launch_bounds__(256)
void k_final(const float* __restrict__ x, const float* __restrict__ st3,
             float* __restrict__ out) {
  const int t  = blockIdx.x * 256 + threadIdx.x;
  const int cg = (t & 15) * 4;
  const float4 v  = *reinterpret_cast<const float4*>(out + (size_t)t * 4);
  const float4 xi = *reinterpret_cast<const float4*>(x  + (size_t)t * 4);
  const float4 sc = *reinterpret_cast<const float4*>(st3 + 128 + cg);
  const float4 sh = *reinterpret_cast<const float4*>(st3 + 192 + cg);
  float4 o;
  o.x = fmaf(v.x, sc.x, sh.x) + xi.x;
  o.y = fmaf(v.y, sc.y, sh.y) + xi.y;
  o.z = fmaf(v.z, sc.z, sh.z) + xi.z;
  o.w = fmaf(v.w, sc.w, sh.w) + xi.w;
  *reinterpret_cast<float4*>(out + (size_t)t * 4) = o;
}

// ---------------------------------------------------------------------------
extern "C" void kernel_launch(void* const* d_in, const int* in_sizes, int n_in,
                              void* d_out, int out_size, void* d_ws, size_t ws_size,
                              hipStream_t stream) {
  const float* x    = (const float*)d_in[0];
  const float* w1   = (const float*)d_in[1];
  const float* g1   = (const float*)d_in[2];
  const float* b1   = (const float*)d_in[3];
  const float* w2   = (const float*)d_in[4];
  const float* g2   = (const float*)d_in[5];
  const float* b2   = (const float*)d_in[6];
  const float* w3   = (const float*)d_in[7];
  const float* g3   = (const float*)d_in[8];
  const float* b3   = (const float*)d_in[9];
  const int*   nidx = (const int*)d_in[10];
  const void*  mraw = d_in[11];
  float* out = (float*)d_out;

  const size_t NH   = (size_t)NS * HID;            // 76.8M elements
  const size_t BASE = (size_t)2 * 1024 * 1024;
  const size_t need_A = BASE + NH * 4;             // t1 bf16 + out2 bf16 (~309 MB)
  const size_t need_B = BASE + NH * 2;             // t1 bf16, double gather (~156 MB)
  const size_t need_D = BASE + NH;                 // h1 uint8, double gather (~79 MB)
  const size_t need_F = BASE;                      // recompute tier (~2 MB)

  char* p = (char*)d_ws;
  float*   st    = (float*)p;                  // 3328 floats
  int*     flag  = (int*)(p + 13312);
  uint8_t* cmask = (uint8_t*)(p + 16384);      // 1.8 MB
  float* stats1 = st;          // sum[384],sq[384],scale[384],shift[384]
  float* stats2 = st + 1536;
  float* stats3 = st + 3072;
  const float invN = 1.0f / (float)NS;
  const int NKV = NS * KV;

  if (ws_size < need_F) {
    hipMemcpyAsync(d_out, d_in[0], (size_t)out_size * sizeof(float),
                   hipMemcpyDeviceToDevice, stream);
    return;
  }

  hipMemsetAsync(st, 0, 13312, stream);
  k_detect<<<1, 256, 0, stream>>>((const uint8_t*)mraw, flag);
  k_canon<<<(NKV + 255) / 256, 256, 0, stream>>>(mraw, flag, cmask, NKV);

  dim3 gA((NS + 127) / 128, HID / 128);
  const int gRows128 = (NS + 127) / 128;

  if (ws_size >= need_A) {
    // ---- tier A: t1 bf16 + out2 bf16 materialized (single gather) ----
    u16* t1   = (u16*)(p + BASE);
    u16* out2 = (u16*)(p + BASE + NH * 2);
    k_gemm1<u16, true, false><<<gA, 256, 0, stream>>>(x, w1, t1, stats1, nullptr, nullptr);
    k_finalize<<<1, HID, 0, stream>>>(g1, b1, stats1, HID, invN);
    k_dwconv<u16, u16><<<NS / 64, HID, 0, stream>>>(t1, nidx, cmask, w2,
                                                    stats1 + 768, stats1 + 1152,
                                                    out2, stats2);
    k_finalize<<<1, HID, 0, stream>>>(g2, b2, stats2, HID, invN);
    k_gemm3<u16><<<gRows128, 256, 0, stream>>>(out2, w3, stats2 + 768, stats2 + 1152,
                                               out, stats3);
  } else if (ws_size >= need_B) {
    // ---- tier B: t1 bf16 materialized; out2 recomputed (double gather) ----
    u16* t1 = (u16*)(p + BASE);
    k_gemm1<u16, true, false><<<gA, 256, 0, stream>>>(x, w1, t1, stats1, nullptr, nullptr);
    k_finalize<<<1, HID, 0, stream>>>(g1, b1, stats1, HID, invN);
    k_dw_stats<u16><<<NS / 64, 384, 0, stream>>>(t1, nidx, cmask, w2,
                                                 stats1 + 768, stats1 + 1152, stats2);
    k_finalize<<<1, HID, 0, stream>>>(g2, b2, stats2, HID, invN);
    k_gemm3f<u16><<<gRows128, 256, 0, stream>>>(t1, nidx, cmask, w2, w3,
                                                stats1 + 768, stats1 + 1152,
                                                stats2 + 768, stats2 + 1152,
                                                out, stats3);
  } else if (ws_size >= need_D) {
    // ---- tier D: h1 = relu6(bn1(x@w1)) stored uint8 (step 6/255) ----
    uint8_t* h1 = (uint8_t*)(p + BASE);
    k_gemm1<u16, false, false><<<gA, 256, 0, stream>>>(x, w1, (u16*)nullptr, stats1,
                                                       nullptr, nullptr);
    k_finalize<<<1, HID, 0, stream>>>(g1, b1, stats1, HID, invN);
    k_gemm1<uint8_t, true, true><<<gA, 256, 0, stream>>>(x, w1, h1, stats1,
                                                         stats1 + 768, stats1 + 1152);
    k_dw_stats<uint8_t><<<NS / 64, 384, 0, stream>>>(h1, nidx, cmask, w2,
                                                     stats1 + 768, stats1 + 1152, stats2);
    k_finalize<<<1, HID, 0, stream>>>(g2, b2, stats2, HID, invN);
    k_gemm3f<uint8_t><<<gRows128, 256, 0, stream>>>(h1, nidx, cmask, w2, w3,
                                                    stats1 + 768, stats1 + 1152,
                                                    stats2 + 768, stats2 + 1152,
                                                    out, stats3);
  } else {
    // ---- tier F: tiny-workspace recompute ----
    k_gemm1<u16, false, false><<<gA, 256, 0, stream>>>(x, w1, (u16*)nullptr, stats1,
                                                       nullptr, nullptr);
    k_finalize<<<1, HID, 0, stream>>>(g1, b1, stats1, HID, invN);
    k_dw_stats_recomp<<<NS / 64, HID, 0, stream>>>(x, w1, nidx, cmask, w2,
                                                   stats1 + 768, stats1 + 1152, stats2);
    k_finalize<<<1, HID, 0, stream>>>(g2, b2, stats2, HID, invN);
    k_gemm3_recomp<<<NS / 32, HID, 0, stream>>>(x, w1, nidx, cmask, w2, w3,
                                                stats1 + 768, stats1 + 1152,
                                                stats2 + 768, stats2 + 1152,
                                                out, stats3);
  }

  k_finalize<<<1, COUT, 0, stream>>>(g3, b3, stats3, COUT, invN);
  k_final<<<(NS * COUT / 4) / 256, 256, 0, stream>>>(x, stats3, out);
}

// Round 7
// 1348.518 us; speedup vs baseline: 6.6505x; 1.6671x over previous
//
#include <hip/hip_runtime.h>
#include <cstdint>
#include <cstddef>

#define NS   200000
#define CIN  64
#define HID  384
#define COUT 64
#define KV   9
#define BN_EPS 1e-5f

typedef unsigned short u16;  // bf16 bits

__device__ __forceinline__ float relu6f(float v) { return fminf(fmaxf(v, 0.f), 6.f); }

__device__ __forceinline__ float bf2f(u16 u) {
  union { unsigned int i; float f; } c; c.i = ((unsigned int)u) << 16; return c.f;
}
__device__ __forceinline__ u16 f2bf(float f) {
  union { float f; unsigned int i; } c; c.f = f;
  unsigned int x = c.i;
  return (u16)((x + 0x7FFFu + ((x >> 16) & 1u)) >> 16);  // RNE
}

// ---- storage-type polymorphic load/store ----
__device__ __forceinline__ float4 ld4(const float* p) { return *reinterpret_cast<const float4*>(p); }
__device__ __forceinline__ float4 ld4(const u16* p) {
  ushort4 u = *reinterpret_cast<const ushort4*>(p);
  return make_float4(bf2f(u.x), bf2f(u.y), bf2f(u.z), bf2f(u.w));
}
__device__ __forceinline__ void st4(float* p, float4 v) { *reinterpret_cast<float4*>(p) = v; }
__device__ __forceinline__ void st4(u16* p, float4 v) {
  ushort4 u; u.x = f2bf(v.x); u.y = f2bf(v.y); u.z = f2bf(v.z); u.w = f2bf(v.w);
  *reinterpret_cast<ushort4*>(p) = u;
}
// uint8 store: input already in [0,6] (relu6 applied) -> quantize step 6/255
__device__ __forceinline__ void st4(uint8_t* p, float4 v) {
  uchar4 u;
  u.x = (uint8_t)(v.x * 42.5f + 0.5f);
  u.y = (uint8_t)(v.y * 42.5f + 0.5f);
  u.z = (uint8_t)(v.z * 42.5f + 0.5f);
  u.w = (uint8_t)(v.w * 42.5f + 0.5f);
  *reinterpret_cast<uchar4*>(p) = u;
}
__device__ __forceinline__ float ld1(const float* p) { return *p; }
__device__ __forceinline__ float ld1(const u16* p) { return bf2f(*p); }
__device__ __forceinline__ void st1(float* p, float v) { *p = v; }
__device__ __forceinline__ void st1(u16* p, float v) { *p = f2bf(v); }

#define U8DQ 0.023529412f  // 6/255

// gather-activation loaders: bf16 raw (apply bn1+relu6) vs u8 pre-activated
__device__ __forceinline__ float4 load_h4(const u16* p, float4 s1, float4 b1) {
  ushort4 v = *reinterpret_cast<const ushort4*>(p);
  return make_float4(relu6f(fmaf(bf2f(v.x), s1.x, b1.x)),
                     relu6f(fmaf(bf2f(v.y), s1.y, b1.y)),
                     relu6f(fmaf(bf2f(v.z), s1.z, b1.z)),
                     relu6f(fmaf(bf2f(v.w), s1.w, b1.w)));
}
__device__ __forceinline__ float4 load_h4(const uint8_t* p, float4, float4) {
  uchar4 v = *reinterpret_cast<const uchar4*>(p);
  return make_float4(v.x * U8DQ, v.y * U8DQ, v.z * U8DQ, v.w * U8DQ);
}

// ---------------------------------------------------------------------------
// Mask layout detection + canonicalization to uint8 (proven in R4).
// ---------------------------------------------------------------------------
__global__ void k_detect(const uint8_t* __restrict__ raw, int* __restrict__ flag) {
  __shared__ int nz[4];
  if (threadIdx.x < 4) nz[threadIdx.x] = 0;
  __syncthreads();
  int cnt[4] = {0, 0, 0, 0};
  const uint8_t* p = raw + threadIdx.x * 16;
#pragma unroll
  for (int j = 0; j < 16; ++j) if (p[j]) cnt[j & 3]++;
#pragma unroll
  for (int r = 0; r < 4; ++r) if (cnt[r]) atomicAdd(&nz[r], cnt[r]);
  __syncthreads();
  if (threadIdx.x == 0) {
    int f;
    if (nz[1] == 0 && nz[2] == 0 && nz[3] == 0) f = 0;       // int32
    else if (nz[0] == 0 && nz[1] == 0)          f = 2;       // float32
    else                                        f = 1;       // uint8
    *flag = f;
  }
}

__global__ __launch_bounds__(256)
void k_canon(const void* __restrict__ raw, const int* __restrict__ flag,
             uint8_t* __restrict__ cmask, int n) {
  const int e = blockIdx.x * 256 + threadIdx.x;
  if (e >= n) return;
  const int f = *flag;
  uint8_t v;
  if (f == 0)      v = ((const int*)raw)[e] != 0;
  else if (f == 1) v = ((const uint8_t*)raw)[e] != 0;
  else             v = ((const float*)raw)[e] != 0.f;
  cmask[e] = v;
}

// ---------------------------------------------------------------------------
// Kernel A: t1 = x @ w1 [NS x HID]. STORE: write t1 (raw, or ACT: bn1+relu6
// applied, e.g. uint8). Stats accumulated only when !ACT.
// Tile 128x128, K=64. 256 threads, 8x8 register blocking.
// ---------------------------------------------------------------------------
template <typename TO, bool STORE, bool ACT>
__global__ __launch_bounds__(256, 2)
void k_gemm1(const float* __restrict__ x, const float* __restrict__ w1,
             TO* __restrict__ t1, float* __restrict__ stats1,
             const float* __restrict__ sc1, const float* __restrict__ sh1) {
  __shared__ float lds[8320 + 8192];
  float* __restrict__ Xs = lds;          // [128][65]
  float* __restrict__ Ws = lds + 8320;   // [64][128]
  const int row0 = blockIdx.x * 128;
  const int col0 = blockIdx.y * 128;
  const int tid  = threadIdx.x;

  {  // stage X tile [m][k], stride 65
    const int k4 = (tid & 15) * 4;
    const int mb = tid >> 4;
#pragma unroll
    for (int it = 0; it < 8; ++it) {
      const int m = mb + it * 16;
      const int r = row0 + m;
      float4 v = make_float4(0.f, 0.f, 0.f, 0.f);
      if (r < NS) v = *reinterpret_cast<const float4*>(x + (size_t)r * CIN + k4);
      float* p = Xs + m * 65 + k4;
      p[0] = v.x; p[1] = v.y; p[2] = v.z; p[3] = v.w;
    }
  }
  {  // stage W tile [k][n]
    const int n4 = (tid & 31) * 4;
    const int kb = tid >> 5;
#pragma unroll
    for (int it = 0; it < 8; ++it) {
      const int k = kb + it * 8;
      *reinterpret_cast<float4*>(Ws + k * 128 + n4) =
          *reinterpret_cast<const float4*>(w1 + k * HID + col0 + n4);
    }
  }
  __syncthreads();

  const int tx = tid & 15, ty = tid >> 4;
  float acc[8][8];
#pragma unroll
  for (int i = 0; i < 8; ++i)
#pragma unroll
    for (int j = 0; j < 8; ++j) acc[i][j] = 0.f;

#pragma unroll 8
  for (int k = 0; k < 64; ++k) {
    float a[8], b[8];
#pragma unroll
    for (int i = 0; i < 4; ++i) {
      a[i]     = Xs[(ty * 4 + i) * 65 + k];
      a[4 + i] = Xs[(64 + ty * 4 + i) * 65 + k];
    }
    float4 b0 = *reinterpret_cast<const float4*>(Ws + k * 128 + tx * 4);
    float4 b1 = *reinterpret_cast<const float4*>(Ws + k * 128 + 64 + tx * 4);
    b[0]=b0.x; b[1]=b0.y; b[2]=b0.z; b[3]=b0.w;
    b[4]=b1.x; b[5]=b1.y; b[6]=b1.z; b[7]=b1.w;
#pragma unroll
    for (int i = 0; i < 8; ++i)
#pragma unroll
      for (int j = 0; j < 8; ++j) acc[i][j] = fmaf(a[i], b[j], acc[i][j]);
  }

  if constexpr (STORE) {
    float4 sA = make_float4(1,1,1,1), bA = make_float4(0,0,0,0);
    float4 sB = sA, bB = bA;
    if constexpr (ACT) {
      sA = *reinterpret_cast<const float4*>(sc1 + col0 + tx * 4);
      bA = *reinterpret_cast<const float4*>(sh1 + col0 + tx * 4);
      sB = *reinterpret_cast<const float4*>(sc1 + col0 + 64 + tx * 4);
      bB = *reinterpret_cast<const float4*>(sh1 + col0 + 64 + tx * 4);
    }
#pragma unroll
    for (int i = 0; i < 8; ++i) {
      const int r = row0 + ((i < 4) ? (ty * 4 + i) : (64 + ty * 4 + i - 4));
      if (r < NS) {
        float4 v0 = make_float4(acc[i][0], acc[i][1], acc[i][2], acc[i][3]);
        float4 v1 = make_float4(acc[i][4], acc[i][5], acc[i][6], acc[i][7]);
        if constexpr (ACT) {
          v0.x = relu6f(fmaf(v0.x, sA.x, bA.x)); v0.y = relu6f(fmaf(v0.y, sA.y, bA.y));
          v0.z = relu6f(fmaf(v0.z, sA.z, bA.z)); v0.w = relu6f(fmaf(v0.w, sA.w, bA.w));
          v1.x = relu6f(fmaf(v1.x, sB.x, bB.x)); v1.y = relu6f(fmaf(v1.y, sB.y, bB.y));
          v1.z = relu6f(fmaf(v1.z, sB.z, bB.z)); v1.w = relu6f(fmaf(v1.w, sB.w, bB.w));
        }
        st4(t1 + (size_t)r * HID + col0 + tx * 4, v0);
        st4(t1 + (size_t)r * HID + col0 + 64 + tx * 4, v1);
      }
    }
  }

  if constexpr (!ACT) {
    float cs[8], cq[8];
#pragma unroll
    for (int j = 0; j < 8; ++j) {
      cs[j] = 0.f; cq[j] = 0.f;
#pragma unroll
      for (int i = 0; i < 8; ++i) { float v = acc[i][j]; cs[j] += v; cq[j] += v * v; }
    }
    __syncthreads();
    float* red = lds;  // [16][256]
#pragma unroll
    for (int j = 0; j < 8; ++j) {
      const int col = (j < 4) ? (tx * 4 + j) : (64 + tx * 4 + j - 4);
      red[ty * 256 + col * 2]     = cs[j];
      red[ty * 256 + col * 2 + 1] = cq[j];
    }
    __syncthreads();
    {
      float s = 0.f;
#pragma unroll
      for (int t = 0; t < 16; ++t) s += red[t * 256 + tid];
      const int col = tid >> 1, st = tid & 1;
      atomicAdd(stats1 + st * HID + col0 + col, s);
    }
  }
}

// ---------------------------------------------------------------------------
// Gather stats pass v2: out2 computed on the fly (NOT stored) -> BN2 sum/sumsq.
// 384 threads = 4 rows x 96 lanes (4 channels each, ushort4 8B loads).
// Branchless mask (indices always valid). Per-thread accumulation over the
// block's 64 rows, LDS reduce across the 4 sub-rows, 1 atomic per address.
// ---------------------------------------------------------------------------
template <typename T>
__global__ __launch_bounds__(384)
void k_dw_stats(const T* __restrict__ h1, const int* __restrict__ nidx,
                const uint8_t* __restrict__ cmask, const float* __restrict__ w2,
                const float* __restrict__ scale1, const float* __restrict__ shift1,
                float* __restrict__ stats2) {
  __shared__ float red[3 * 96 * 9];  // stride 9 pad: conflict-light
  const int tid = threadIdx.x;
  const int sub = tid / 96;          // 0..3
  const int lc  = tid - sub * 96;    // 0..95
  const int c0  = lc * 4;
  const float4 s1 = *reinterpret_cast<const float4*>(scale1 + c0);
  const float4 b1 = *reinterpret_cast<const float4*>(shift1 + c0);
  float4 w2r[KV];
#pragma unroll
  for (int k = 0; k < KV; ++k)
    w2r[k] = *reinterpret_cast<const float4*>(w2 + k * HID + c0);

  const int rowBase = blockIdx.x * 64;
  float4 sum = make_float4(0,0,0,0), sq = make_float4(0,0,0,0);
  for (int r = sub; r < 64; r += 4) {
    const int i = rowBase + r;
    const int*     ip = nidx  + (size_t)i * KV;
    const uint8_t* mp = cmask + (size_t)i * KV;
    float4 a = make_float4(0,0,0,0);
#pragma unroll
    for (int k = 0; k < KV; ++k) {
      const int j = ip[k];
      const float mk = mp[k] ? 1.f : 0.f;
      float4 h = load_h4(h1 + (size_t)j * HID + c0, s1, b1);
      a.x = fmaf(h.x, w2r[k].x * mk, a.x);
      a.y = fmaf(h.y, w2r[k].y * mk, a.y);
      a.z = fmaf(h.z, w2r[k].z * mk, a.z);
      a.w = fmaf(h.w, w2r[k].w * mk, a.w);
    }
    sum.x += a.x; sum.y += a.y; sum.z += a.z; sum.w += a.w;
    sq.x  += a.x * a.x; sq.y += a.y * a.y; sq.z += a.z * a.z; sq.w += a.w * a.w;
  }
  if (sub > 0) {
    float* p = red + ((sub - 1) * 96 + lc) * 9;
    p[0] = sum.x; p[1] = sum.y; p[2] = sum.z; p[3] = sum.w;
    p[4] = sq.x;  p[5] = sq.y;  p[6] = sq.z;  p[7] = sq.w;
  }
  __syncthreads();
  if (sub == 0) {
#pragma unroll
    for (int s = 0; s < 3; ++s) {
      const float* p = red + (s * 96 + lc) * 9;
      sum.x += p[0]; sum.y += p[1]; sum.z += p[2]; sum.w += p[3];
      sq.x  += p[4]; sq.y  += p[5]; sq.z  += p[6]; sq.w  += p[7];
    }
    atomicAdd(stats2 + c0,     sum.x);
    atomicAdd(stats2 + c0 + 1, sum.y);
    atomicAdd(stats2 + c0 + 2, sum.z);
    atomicAdd(stats2 + c0 + 3, sum.w);
    atomicAdd(stats2 + HID + c0,     sq.x);
    atomicAdd(stats2 + HID + c0 + 1, sq.y);
    atomicAdd(stats2 + HID + c0 + 2, sq.z);
    atomicAdd(stats2 + HID + c0 + 3, sq.w);
  }
}

// ---------------------------------------------------------------------------
// Fused gemm3 v2: A-tile staged by RECOMPUTING out2 rows (gather from
// L3-resident h1/t1), then bn2+relu6, then GEMM with w3 -> d_out + BN3 stats.
// Tile 64x64, K chunked by 64. 256 threads, 2x8 blocking.
// LDS 35 KB -> 4 blocks/CU (occupancy 50%). Branchless gather.
// ---------------------------------------------------------------------------
template <typename T>
__global__ __launch_bounds__(256, 4)
void k_gemm3f(const T* __restrict__ h1, const int* __restrict__ nidx,
              const uint8_t* __restrict__ cmask, const float* __restrict__ w2,
              const float* __restrict__ w3,
              const float* __restrict__ sc1v, const float* __restrict__ sh1v,
              const float* __restrict__ sc2v, const float* __restrict__ sh2v,
              float* __restrict__ out, float* __restrict__ stats3) {
  __shared__ float lds[4160 + 4096 + 576];
  float* __restrict__ As  = lds;                 // [64][65]
  float* __restrict__ Ws  = lds + 4160;          // [64][64]
  float* __restrict__ W2s = lds + 4160 + 4096;   // [9][64]
  const int row0 = blockIdx.x * 64;              // NS = 64*3125 exact
  const int tid  = threadIdx.x;
  const int tx = tid & 7, ty = tid >> 3;         // 8 x 32

  float acc[2][8];
#pragma unroll
  for (int i = 0; i < 2; ++i)
#pragma unroll
    for (int j = 0; j < 8; ++j) acc[i][j] = 0.f;

  for (int kc = 0; kc < HID; kc += 64) {
    // stage w2 chunk [9][64]
    if (tid < 144) {
      const int k = tid / 16, q4 = (tid & 15) * 4;
      *reinterpret_cast<float4*>(W2s + k * 64 + q4) =
          *reinterpret_cast<const float4*>(w2 + k * HID + kc + q4);
    }
    __syncthreads();

    {  // stage A: recompute out2 rows via branchless gather, apply bn2+relu6
      const int k4 = (tid & 15) * 4;
      const int mb = tid >> 4;                   // 0..15
      const float4 s1 = *reinterpret_cast<const float4*>(sc1v + kc + k4);
      const float4 b1 = *reinterpret_cast<const float4*>(sh1v + kc + k4);
      const float4 s2 = *reinterpret_cast<const float4*>(sc2v + kc + k4);
      const float4 b2 = *reinterpret_cast<const float4*>(sh2v + kc + k4);
#pragma unroll
      for (int it = 0; it < 4; ++it) {
        const int m = mb + it * 16;
        const int i = row0 + m;
        const int*     ip = nidx  + (size_t)i * KV;
        const uint8_t* mp = cmask + (size_t)i * KV;
        float4 a = make_float4(0.f, 0.f, 0.f, 0.f);
#pragma unroll
        for (int k = 0; k < KV; ++k) {
          const int j = ip[k];
          const float mk = mp[k] ? 1.f : 0.f;
          float4 h = load_h4(h1 + (size_t)j * HID + kc + k4, s1, b1);
          a.x = fmaf(h.x, W2s[k * 64 + k4]     * mk, a.x);
          a.y = fmaf(h.y, W2s[k * 64 + k4 + 1] * mk, a.y);
          a.z = fmaf(h.z, W2s[k * 64 + k4 + 2] * mk, a.z);
          a.w = fmaf(h.w, W2s[k * 64 + k4 + 3] * mk, a.w);
        }
        float* p = As + m * 65 + k4;
        p[0] = relu6f(fmaf(a.x, s2.x, b2.x));
        p[1] = relu6f(fmaf(a.y, s2.y, b2.y));
        p[2] = relu6f(fmaf(a.z, s2.z, b2.z));
        p[3] = relu6f(fmaf(a.w, s2.w, b2.w));
      }
    }
    {  // stage W3 chunk [64][64]
      const int n4 = (tid & 15) * 4;
      const int kb = tid >> 4;
#pragma unroll
      for (int it = 0; it < 4; ++it) {
        const int k = kb + it * 16;
        *reinterpret_cast<float4*>(Ws + k * 64 + n4) =
            *reinterpret_cast<const float4*>(w3 + (size_t)(kc + k) * COUT + n4);
      }
    }
    __syncthreads();

#pragma unroll 8
    for (int k = 0; k < 64; ++k) {
      float a[2], b[8];
#pragma unroll
      for (int i = 0; i < 2; ++i) a[i] = As[(ty * 2 + i) * 65 + k];
      float4 b0 = *reinterpret_cast<const float4*>(Ws + k * 64 + tx * 4);
      float4 b1 = *reinterpret_cast<const float4*>(Ws + k * 64 + 32 + tx * 4);
      b[0]=b0.x; b[1]=b0.y; b[2]=b0.z; b[3]=b0.w;
      b[4]=b1.x; b[5]=b1.y; b[6]=b1.z; b[7]=b1.w;
#pragma unroll
      for (int i = 0; i < 2; ++i)
#pragma unroll
        for (int j = 0; j < 8; ++j) acc[i][j] = fmaf(a[i], b[j], acc[i][j]);
    }
    __syncthreads();
  }

#pragma unroll
  for (int i = 0; i < 2; ++i) {
    const int r = row0 + ty * 2 + i;
    *reinterpret_cast<float4*>(out + (size_t)r * COUT + tx * 4) =
        make_float4(acc[i][0], acc[i][1], acc[i][2], acc[i][3]);
    *reinterpret_cast<float4*>(out + (size_t)r * COUT + 32 + tx * 4) =
        make_float4(acc[i][4], acc[i][5], acc[i][6], acc[i][7]);
  }

  float cs[8], cq[8];
#pragma unroll
  for (int j = 0; j < 8; ++j) {
    cs[j] = 0.f; cq[j] = 0.f;
#pragma unroll
    for (int i = 0; i < 2; ++i) { float v = acc[i][j]; cs[j] += v; cq[j] += v * v; }
  }
  __syncthreads();
  float* red = lds;  // [32][128]
#pragma unroll
  for (int j = 0; j < 8; ++j) {
    const int col = (j < 4) ? (tx * 4 + j) : (32 + tx * 4 + j - 4);
    red[ty * 128 + col * 2]     = cs[j];
    red[ty * 128 + col * 2 + 1] = cq[j];
  }
  __syncthreads();
  if (tid < 128) {
    float s = 0.f;
#pragma unroll
    for (int t = 0; t < 32; ++t) s += red[t * 128 + tid];
    const int col = tid >> 1, st = tid & 1;
    atomicAdd(stats3 + st * COUT + col, s);
  }
}

// ---------------------------------------------------------------------------
// Tier A kernels (materialized out2) — kept for large-ws case.
// ---------------------------------------------------------------------------
template <typename TI, typename TO>
__global__ __launch_bounds__(384)
void k_dwconv(const TI* __restrict__ t1, const int* __restrict__ nidx,
              const uint8_t* __restrict__ cmask, const float* __restrict__ w2,
              const float* __restrict__ scale1, const float* __restrict__ shift1,
              TO* __restrict__ out2, float* __restrict__ stats2) {
  const int c  = threadIdx.x;
  const float s1 = scale1[c];
  const float b1 = shift1[c];
  float w2r[KV];
#pragma unroll
  for (int k = 0; k < KV; ++k) w2r[k] = w2[k * HID + c];
  const int rowBase = blockIdx.x * 64;
  float sum = 0.f, sq = 0.f;
  for (int r = 0; r < 64; ++r) {
    const int i = rowBase + r;
    const int*     ip = nidx  + (size_t)i * KV;
    const uint8_t* mp = cmask + (size_t)i * KV;
    float acc = 0.f;
#pragma unroll
    for (int k = 0; k < KV; ++k) {
      if (mp[k]) {
        const int j = ip[k];
        const float v = ld1(t1 + (size_t)j * HID + c);
        const float h = relu6f(fmaf(v, s1, b1));
        acc = fmaf(h, w2r[k], acc);
      }
    }
    st1(out2 + (size_t)i * HID + c, acc);
    sum += acc; sq += acc * acc;
  }
  atomicAdd(stats2 + c,       sum);
  atomicAdd(stats2 + HID + c, sq);
}

template <typename TI>
__global__ __launch_bounds__(256, 3)
void k_gemm3(const TI* __restrict__ out2, const float* __restrict__ w3,
             const float* __restrict__ scale2, const float* __restrict__ shift2,
             float* __restrict__ t3, float* __restrict__ stats3) {
  __shared__ float lds[8320 + 4096];
  float* __restrict__ As = lds;          // [128][65]
  float* __restrict__ Ws = lds + 8320;   // [64][64]
  const int row0 = blockIdx.x * 128;
  const int tid  = threadIdx.x;
  const int tx = tid & 7, ty = tid >> 3;
  float acc[4][8];
#pragma unroll
  for (int i = 0; i < 4; ++i)
#pragma unroll
    for (int j = 0; j < 8; ++j) acc[i][j] = 0.f;

  for (int kc = 0; kc < HID; kc += 64) {
    {
      const int k4 = (tid & 15) * 4;
      const int mb = tid >> 4;
      const float4 sc = *reinterpret_cast<const float4*>(scale2 + kc + k4);
      const float4 sh = *reinterpret_cast<const float4*>(shift2 + kc + k4);
#pragma unroll
      for (int it = 0; it < 8; ++it) {
        const int m = mb + it * 16;
        const int r = row0 + m;
        float4 o = make_float4(0.f, 0.f, 0.f, 0.f);
        if (r < NS) {
          const float4 v = ld4(out2 + (size_t)r * HID + kc + k4);
          o.x = relu6f(fmaf(v.x, sc.x, sh.x));
          o.y = relu6f(fmaf(v.y, sc.y, sh.y));
          o.z = relu6f(fmaf(v.z, sc.z, sh.z));
          o.w = relu6f(fmaf(v.w, sc.w, sh.w));
        }
        float* p = As + m * 65 + k4;
        p[0] = o.x; p[1] = o.y; p[2] = o.z; p[3] = o.w;
      }
    }
    {
      const int n4 = (tid & 15) * 4;
      const int kb = tid >> 4;
#pragma unroll
      for (int it = 0; it < 4; ++it) {
        const int k = kb + it * 16;
        *reinterpret_cast<float4*>(Ws + k * 64 + n4) =
            *reinterpret_cast<const float4*>(w3 + (size_t)(kc + k) * COUT + n4);
      }
    }
    __syncthreads();
#pragma unroll 8
    for (int k = 0; k < 64; ++k) {
      float a[4], b[8];
#pragma unroll
      for (int i = 0; i < 4; ++i) a[i] = As[(ty * 4 + i) * 65 + k];
      float4 b0 = *reinterpret_cast<const float4*>(Ws + k * 64 + tx * 4);
      float4 b1 = *reinterpret_cast<const float4*>(Ws + k * 64 + 32 + tx * 4);
      b[0]=b0.x; b[1]=b0.y; b[2]=b0.z; b[3]=b0.w;
      b[4]=b1.x; b[5]=b1.y; b[6]=b1.z; b[7]=b1.w;
#pragma unroll
      for (int i = 0; i < 4; ++i)
#pragma unroll
        for (int j = 0; j < 8; ++j) acc[i][j] = fmaf(a[i], b[j], acc[i][j]);
    }
    __syncthreads();
  }
#pragma unroll
  for (int i = 0; i < 4; ++i) {
    const int r = row0 + ty * 4 + i;
    if (r < NS) {
      *reinterpret_cast<float4*>(t3 + (size_t)r * COUT + tx * 4) =
          make_float4(acc[i][0], acc[i][1], acc[i][2], acc[i][3]);
      *reinterpret_cast<float4*>(t3 + (size_t)r * COUT + 32 + tx * 4) =
          make_float4(acc[i][4], acc[i][5], acc[i][6], acc[i][7]);
    }
  }
  float cs[8], cq[8];
#pragma unroll
  for (int j = 0; j < 8; ++j) {
    cs[j] = 0.f; cq[j] = 0.f;
#pragma unroll
    for (int i = 0; i < 4; ++i) { float v = acc[i][j]; cs[j] += v; cq[j] += v * v; }
  }
  __syncthreads();
  float* red = lds;
#pragma unroll
  for (int j = 0; j < 8; ++j) {
    const int col = (j < 4) ? (tx * 4 + j) : (32 + tx * 4 + j - 4);
    red[ty * 128 + col * 2]     = cs[j];
    red[ty * 128 + col * 2 + 1] = cq[j];
  }
  __syncthreads();
  if (tid < 128) {
    float s = 0.f;
#pragma unroll
    for (int t = 0; t < 32; ++t) s += red[t * 128 + tid];
    const int col = tid >> 1, st = tid & 1;
    atomicAdd(stats3 + st * COUT + col, s);
  }
}

// ---------------------------------------------------------------------------
// Tier F (tiny workspace) — unchanged recompute fallback from R4.
// ---------------------------------------------------------------------------
__global__ __launch_bounds__(384)
void k_dw_stats_recomp(const float* __restrict__ x, const float* __restrict__ w1,
                       const int* __restrict__ nidx, const uint8_t* __restrict__ cmask,
                       const float* __restrict__ w2,
                       const float* __restrict__ scale1, const float* __restrict__ shift1,
                       float* __restrict__ stats2) {
  __shared__ u16   W1s[64 * 384];
  __shared__ float xb[KV][64];
  const int c = threadIdx.x;
#pragma unroll
  for (int it = 0; it < 16; ++it) {
    const int idx4 = it * 384 + c;
    float4 v = *reinterpret_cast<const float4*>(w1 + idx4 * 4);
    ushort4 u; u.x = f2bf(v.x); u.y = f2bf(v.y); u.z = f2bf(v.z); u.w = f2bf(v.w);
    *reinterpret_cast<ushort4*>(W1s + idx4 * 4) = u;
  }
  const float s1 = scale1[c], b1 = shift1[c];
  float w2r[KV];
#pragma unroll
  for (int k = 0; k < KV; ++k) w2r[k] = w2[k * HID + c];
  const int rowBase = blockIdx.x * 64;
  float sum = 0.f, sq = 0.f;
  for (int r = 0; r < 64; ++r) {
    const int i = rowBase + r;
    __syncthreads();
    if (c < 144) {
      const int k = c >> 4, q = c & 15;
      const int j = nidx[(size_t)i * KV + k];
      *reinterpret_cast<float4*>(&xb[k][q * 4]) =
          *reinterpret_cast<const float4*>(x + (size_t)j * CIN + q * 4);
    }
    __syncthreads();
    const uint8_t* mp = cmask + (size_t)i * KV;
    float acc = 0.f;
#pragma unroll
    for (int k = 0; k < KV; ++k) {
      if (mp[k]) {
        float t = 0.f;
#pragma unroll
        for (int kk = 0; kk < 64; ++kk)
          t = fmaf(xb[k][kk], bf2f(W1s[kk * 384 + c]), t);
        acc = fmaf(relu6f(fmaf(t, s1, b1)), w2r[k], acc);
      }
    }
    sum += acc; sq += acc * acc;
  }
  atomicAdd(stats2 + c,       sum);
  atomicAdd(stats2 + HID + c, sq);
}

__global__ __launch_bounds__(384)
void k_gemm3_recomp(const float* __restrict__ x, const float* __restrict__ w1,
                    const int* __restrict__ nidx, const uint8_t* __restrict__ cmask,
                    const float* __restrict__ w2, const float* __restrict__ w3,
                    const float* __restrict__ scale1, const float* __restrict__ shift1,
                    const float* __restrict__ scale2, const float* __restrict__ shift2,
                    float* __restrict__ out, float* __restrict__ stats3) {
  __shared__ u16   W1s[64 * 384];
  __shared__ float xb[KV][64];
  __shared__ float h2[HID];
  __shared__ float part[6][64];
  const int c = threadIdx.x;
#pragma unroll
  for (int it = 0; it < 16; ++it) {
    const int idx4 = it * 384 + c;
    float4 v = *reinterpret_cast<const float4*>(w1 + idx4 * 4);
    ushort4 u; u.x = f2bf(v.x); u.y = f2bf(v.y); u.z = f2bf(v.z); u.w = f2bf(v.w);
    *reinterpret_cast<ushort4*>(W1s + idx4 * 4) = u;
  }
  const float s1 = scale1[c], b1 = shift1[c];
  const float s2 = scale2[c], b2 = shift2[c];
  float w2r[KV];
#pragma unroll
  for (int k = 0; k < KV; ++k) w2r[k] = w2[k * HID + c];
  const int wv = c >> 6;
  const int ln = c & 63;
  float ssum = 0.f, ssq = 0.f;
  const int rowBase = blockIdx.x * 32;
  for (int r = 0; r < 32; ++r) {
    const int i = rowBase + r;
    __syncthreads();
    if (c < 144) {
      const int k = c >> 4, q = c & 15;
      const int j = nidx[(size_t)i * KV + k];
      *reinterpret_cast<float4*>(&xb[k][q * 4]) =
          *reinterpret_cast<const float4*>(x + (size_t)j * CIN + q * 4);
    }
    __syncthreads();
    const uint8_t* mp = cmask + (size_t)i * KV;
    float acc = 0.f;
#pragma unroll
    for (int k = 0; k < KV; ++k) {
      if (mp[k]) {
        float t = 0.f;
#pragma unroll
        for (int kk = 0; kk < 64; ++kk)
          t = fmaf(xb[k][kk], bf2f(W1s[kk * 384 + c]), t);
        acc = fmaf(relu6f(fmaf(t, s1, b1)), w2r[k], acc);
      }
    }
    h2[c] = relu6f(fmaf(acc, s2, b2));
    __syncthreads();
    float pt = 0.f;
#pragma unroll
    for (int cc = 0; cc < 64; ++cc) {
      const int ch = wv * 64 + cc;
      pt = fmaf(h2[ch], w3[ch * COUT + ln], pt);
    }
    part[wv][ln] = pt;
    __syncthreads();
    if (c < 64) {
      const float t3 = part[0][c] + part[1][c] + part[2][c] +
                       part[3][c] + part[4][c] + part[5][c];
      out[(size_t)i * COUT + c] = t3;
      ssum += t3; ssq += t3 * t3;
    }
  }
  if (c < 64) {
    atomicAdd(stats3 + c,        ssum);
    atomicAdd(stats3 + COUT + c, ssq);
  }
}

// ---------------------------------------------------------------------------
__global__ void k_finalize(const float* __restrict__ gamma, const float* __restrict__ beta,
                           float* __restrict__ stats, int C, float invN) {
  const int c = blockIdx.x * blockDim.x + threadIdx.x;
  if (c >= C) return;
  const float mean = stats[c] * invN;
  const float var  = stats[C + c] * invN - mean * mean;
  const float sc   = gamma[c] / sqrtf(var + BN_EPS);
  stats[2 * C + c] = sc;
  stats[3 * C + c] = fmaf(-mean, sc, beta[c]);
}

__global__ __launch_bounds__(256)
void k_final(const float* __restrict__ x, const float* __restrict__ st3,
             float* __restrict__ out) {
  const int t  = blockIdx.x * 256 + threadIdx.x;
  const int cg = (t & 15) * 4;
  const float4 v  = *reinterpret_cast<const float4*>(out + (size_t)t * 4);
  const float4 xi = *reinterpret_cast<const float4*>(x  + (size_t)t * 4);
  const float4 sc = *reinterpret_cast<const float4*>(st3 + 128 + cg);
  const float4 sh = *reinterpret_cast<const float4*>(st3 + 192 + cg);
  float4 o;
  o.x = fmaf(v.x, sc.x, sh.x) + xi.x;
  o.y = fmaf(v.y, sc.y, sh.y) + xi.y;
  o.z = fmaf(v.z, sc.z, sh.z) + xi.z;
  o.w = fmaf(v.w, sc.w, sh.w) + xi.w;
  *reinterpret_cast<float4*>(out + (size_t)t * 4) = o;
}

// ---------------------------------------------------------------------------
extern "C" void kernel_launch(void* const* d_in, const int* in_sizes, int n_in,
                              void* d_out, int out_size, void* d_ws, size_t ws_size,
                              hipStream_t stream) {
  const float* x    = (const float*)d_in[0];
  const float* w1   = (const float*)d_in[1];
  const float* g1   = (const float*)d_in[2];
  const float* b1   = (const float*)d_in[3];
  const float* w2   = (const float*)d_in[4];
  const float* g2   = (const float*)d_in[5];
  const float* b2   = (const float*)d_in[6];
  const float* w3   = (const float*)d_in[7];
  const float* g3   = (const float*)d_in[8];
  const float* b3   = (const float*)d_in[9];
  const int*   nidx = (const int*)d_in[10];
  const void*  mraw = d_in[11];
  float* out = (float*)d_out;

  const size_t NH   = (size_t)NS * HID;            // 76.8M elements
  const size_t BASE = (size_t)2 * 1024 * 1024;
  const size_t need_A = BASE + NH * 4;             // t1 bf16 + out2 bf16 (~309 MB)
  const size_t need_B = BASE + NH * 2;             // t1 bf16, double gather (~156 MB)
  const size_t need_D = BASE + NH;                 // h1 uint8, double gather (~79 MB)
  const size_t need_F = BASE;                      // recompute tier (~2 MB)

  char* p = (char*)d_ws;
  float*   st    = (float*)p;                  // 3328 floats
  int*     flag  = (int*)(p + 13312);
  uint8_t* cmask = (uint8_t*)(p + 16384);      // 1.8 MB
  float* stats1 = st;          // sum[384],sq[384],scale[384],shift[384]
  float* stats2 = st + 1536;
  float* stats3 = st + 3072;
  const float invN = 1.0f / (float)NS;
  const int NKV = NS * KV;

  if (ws_size < need_F) {
    hipMemcpyAsync(d_out, d_in[0], (size_t)out_size * sizeof(float),
                   hipMemcpyDeviceToDevice, stream);
    return;
  }

  hipMemsetAsync(st, 0, 13312, stream);
  k_detect<<<1, 256, 0, stream>>>((const uint8_t*)mraw, flag);
  k_canon<<<(NKV + 255) / 256, 256, 0, stream>>>(mraw, flag, cmask, NKV);

  dim3 gA((NS + 127) / 128, HID / 128);
  const int gRows128 = (NS + 127) / 128;
  const int gRows64  = NS / 64;                // 3125, exact

  if (ws_size >= need_A) {
    // ---- tier A: t1 bf16 + out2 bf16 materialized (single gather) ----
    u16* t1   = (u16*)(p + BASE);
    u16* out2 = (u16*)(p + BASE + NH * 2);
    k_gemm1<u16, true, false><<<gA, 256, 0, stream>>>(x, w1, t1, stats1, nullptr, nullptr);
    k_finalize<<<1, HID, 0, stream>>>(g1, b1, stats1, HID, invN);
    k_dwconv<u16, u16><<<gRows64, HID, 0, stream>>>(t1, nidx, cmask, w2,
                                                    stats1 + 768, stats1 + 1152,
                                                    out2, stats2);
    k_finalize<<<1, HID, 0, stream>>>(g2, b2, stats2, HID, invN);
    k_gemm3<u16><<<gRows128, 256, 0, stream>>>(out2, w3, stats2 + 768, stats2 + 1152,
                                               out, stats3);
  } else if (ws_size >= need_B) {
    // ---- tier B: t1 bf16 materialized; out2 recomputed (double gather) ----
    u16* t1 = (u16*)(p + BASE);
    k_gemm1<u16, true, false><<<gA, 256, 0, stream>>>(x, w1, t1, stats1, nullptr, nullptr);
    k_finalize<<<1, HID, 0, stream>>>(g1, b1, stats1, HID, invN);
    k_dw_stats<u16><<<gRows64, 384, 0, stream>>>(t1, nidx, cmask, w2,
                                                 stats1 + 768, stats1 + 1152, stats2);
    k_finalize<<<1, HID, 0, stream>>>(g2, b2, stats2, HID, invN);
    k_gemm3f<u16><<<gRows64, 256, 0, stream>>>(t1, nidx, cmask, w2, w3,
                                               stats1 + 768, stats1 + 1152,
                                               stats2 + 768, stats2 + 1152,
                                               out, stats3);
  } else if (ws_size >= need_D) {
    // ---- tier D: h1 = relu6(bn1(x@w1)) stored uint8 (step 6/255) ----
    uint8_t* h1 = (uint8_t*)(p + BASE);
    k_gemm1<u16, false, false><<<gA, 256, 0, stream>>>(x, w1, (u16*)nullptr, stats1,
                                                       nullptr, nullptr);
    k_finalize<<<1, HID, 0, stream>>>(g1, b1, stats1, HID, invN);
    k_gemm1<uint8_t, true, true><<<gA, 256, 0, stream>>>(x, w1, h1, stats1,
                                                         stats1 + 768, stats1 + 1152);
    k_dw_stats<uint8_t><<<gRows64, 384, 0, stream>>>(h1, nidx, cmask, w2,
                                                     stats1 + 768, stats1 + 1152, stats2);
    k_finalize<<<1, HID, 0, stream>>>(g2, b2, stats2, HID, invN);
    k_gemm3f<uint8_t><<<gRows64, 256, 0, stream>>>(h1, nidx, cmask, w2, w3,
                                                   stats1 + 768, stats1 + 1152,
                                                   stats2 + 768, stats2 + 1152,
                                                   out, stats3);
  } else {
    // ---- tier F: tiny-workspace recompute ----
    k_gemm1<u16, false, false><<<gA, 256, 0, stream>>>(x, w1, (u16*)nullptr, stats1,
                                                       nullptr, nullptr);
    k_finalize<<<1, HID, 0, stream>>>(g1, b1, stats1, HID, invN);
    k_dw_stats_recomp<<<gRows64, HID, 0, stream>>>(x, w1, nidx, cmask, w2,
                                                   stats1 + 768, stats1 + 1152, stats2);
    k_finalize<<<1, HID, 0, stream>>>(g2, b2, stats2, HID, invN);
    k_gemm3_recomp<<<NS / 32, HID, 0, stream>>>(x, w1, nidx, cmask, w2, w3,
                                                stats1 + 768, stats1 + 1152,
                                                stats2 + 768, stats2 + 1152,
                                                out, stats3);
  }

  k_finalize<<<1, COUT, 0, stream>>>(g3, b3, stats3, COUT, invN);
  k_final<<<(NS * COUT / 4) / 256, 256, 0, stream>>>(x, stats3, out);
}

// Round 9
// 860.016 us; speedup vs baseline: 10.4281x; 1.5680x over previous
//
#include <hip/hip_runtime.h>
#include <cstdint>
#include <cstddef>

#define NS   200000
#define CIN  64
#define HID  384
#define COUT 64
#define KV   9
#define BN_EPS 1e-5f

typedef unsigned short u16;  // bf16 bits

__device__ __forceinline__ float relu6f(float v) { return fminf(fmaxf(v, 0.f), 6.f); }

__device__ __forceinline__ float bf2f(u16 u) {
  union { unsigned int i; float f; } c; c.i = ((unsigned int)u) << 16; return c.f;
}
__device__ __forceinline__ u16 f2bf(float f) {
  union { float f; unsigned int i; } c; c.f = f;
  unsigned int x = c.i;
  return (u16)((x + 0x7FFFu + ((x >> 16) & 1u)) >> 16);  // RNE
}

// ---- storage-type polymorphic load/store ----
__device__ __forceinline__ float4 ld4(const float* p) { return *reinterpret_cast<const float4*>(p); }
__device__ __forceinline__ float4 ld4(const u16* p) {
  ushort4 u = *reinterpret_cast<const ushort4*>(p);
  return make_float4(bf2f(u.x), bf2f(u.y), bf2f(u.z), bf2f(u.w));
}
__device__ __forceinline__ void st4(float* p, float4 v) { *reinterpret_cast<float4*>(p) = v; }
__device__ __forceinline__ void st4(u16* p, float4 v) {
  ushort4 u; u.x = f2bf(v.x); u.y = f2bf(v.y); u.z = f2bf(v.z); u.w = f2bf(v.w);
  *reinterpret_cast<ushort4*>(p) = u;
}
// uint8 store: input already in [0,6] (relu6 applied) -> quantize step 6/255
__device__ __forceinline__ void st4(uint8_t* p, float4 v) {
  uchar4 u;
  u.x = (uint8_t)(v.x * 42.5f + 0.5f);
  u.y = (uint8_t)(v.y * 42.5f + 0.5f);
  u.z = (uint8_t)(v.z * 42.5f + 0.5f);
  u.w = (uint8_t)(v.w * 42.5f + 0.5f);
  *reinterpret_cast<uchar4*>(p) = u;
}
__device__ __forceinline__ float ld1(const float* p) { return *p; }
__device__ __forceinline__ float ld1(const u16* p) { return bf2f(*p); }
__device__ __forceinline__ void st1(float* p, float v) { *p = v; }
__device__ __forceinline__ void st1(u16* p, float v) { *p = f2bf(v); }

#define U8DQ 0.023529412f  // 6/255

// gather-activation loaders: bf16 raw (apply bn1+relu6) vs u8 pre-activated
__device__ __forceinline__ float4 load_h4(const u16* p, float4 s1, float4 b1) {
  ushort4 v = *reinterpret_cast<const ushort4*>(p);
  return make_float4(relu6f(fmaf(bf2f(v.x), s1.x, b1.x)),
                     relu6f(fmaf(bf2f(v.y), s1.y, b1.y)),
                     relu6f(fmaf(bf2f(v.z), s1.z, b1.z)),
                     relu6f(fmaf(bf2f(v.w), s1.w, b1.w)));
}
__device__ __forceinline__ float4 load_h4(const uint8_t* p, float4, float4) {
  uchar4 v = *reinterpret_cast<const uchar4*>(p);
  return make_float4(v.x * U8DQ, v.y * U8DQ, v.z * U8DQ, v.w * U8DQ);
}

// ---------------------------------------------------------------------------
// Mask layout detection + canonicalization to uint8 (proven in R4).
// ---------------------------------------------------------------------------
__global__ void k_detect(const uint8_t* __restrict__ raw, int* __restrict__ flag) {
  __shared__ int nz[4];
  if (threadIdx.x < 4) nz[threadIdx.x] = 0;
  __syncthreads();
  int cnt[4] = {0, 0, 0, 0};
  const uint8_t* p = raw + threadIdx.x * 16;
#pragma unroll
  for (int j = 0; j < 16; ++j) if (p[j]) cnt[j & 3]++;
#pragma unroll
  for (int r = 0; r < 4; ++r) if (cnt[r]) atomicAdd(&nz[r], cnt[r]);
  __syncthreads();
  if (threadIdx.x == 0) {
    int f;
    if (nz[1] == 0 && nz[2] == 0 && nz[3] == 0) f = 0;       // int32
    else if (nz[0] == 0 && nz[1] == 0)          f = 2;       // float32
    else                                        f = 1;       // uint8
    *flag = f;
  }
}

__global__ __launch_bounds__(256)
void k_canon(const void* __restrict__ raw, const int* __restrict__ flag,
             uint8_t* __restrict__ cmask, int n) {
  const int e = blockIdx.x * 256 + threadIdx.x;
  if (e >= n) return;
  const int f = *flag;
  uint8_t v;
  if (f == 0)      v = ((const int*)raw)[e] != 0;
  else if (f == 1) v = ((const uint8_t*)raw)[e] != 0;
  else             v = ((const float*)raw)[e] != 0.f;
  cmask[e] = v;
}

// ---------------------------------------------------------------------------
// Kernel A: t1 = x @ w1 [NS x HID]. STORE: write t1 (raw, or ACT: bn1+relu6
// applied, e.g. uint8). Stats accumulated only when !ACT.
// Tile 128x128, K=64. 256 threads, 8x8 register blocking.
// ---------------------------------------------------------------------------
template <typename TO, bool STORE, bool ACT>
__global__ __launch_bounds__(256, 2)
void k_gemm1(const float* __restrict__ x, const float* __restrict__ w1,
             TO* __restrict__ t1, float* __restrict__ stats1,
             const float* __restrict__ sc1, const float* __restrict__ sh1) {
  __shared__ float lds[8320 + 8192];
  float* __restrict__ Xs = lds;          // [128][65]
  float* __restrict__ Ws = lds + 8320;   // [64][128]
  const int row0 = blockIdx.x * 128;
  const int col0 = blockIdx.y * 128;
  const int tid  = threadIdx.x;

  {  // stage X tile [m][k], stride 65
    const int k4 = (tid & 15) * 4;
    const int mb = tid >> 4;
#pragma unroll
    for (int it = 0; it < 8; ++it) {
      const int m = mb + it * 16;
      const int r = row0 + m;
      float4 v = make_float4(0.f, 0.f, 0.f, 0.f);
      if (r < NS) v = *reinterpret_cast<const float4*>(x + (size_t)r * CIN + k4);
      float* p = Xs + m * 65 + k4;
      p[0] = v.x; p[1] = v.y; p[2] = v.z; p[3] = v.w;
    }
  }
  {  // stage W tile [k][n]
    const int n4 = (tid & 31) * 4;
    const int kb = tid >> 5;
#pragma unroll
    for (int it = 0; it < 8; ++it) {
      const int k = kb + it * 8;
      *reinterpret_cast<float4*>(Ws + k * 128 + n4) =
          *reinterpret_cast<const float4*>(w1 + k * HID + col0 + n4);
    }
  }
  __syncthreads();

  const int tx = tid & 15, ty = tid >> 4;
  float acc[8][8];
#pragma unroll
  for (int i = 0; i < 8; ++i)
#pragma unroll
    for (int j = 0; j < 8; ++j) acc[i][j] = 0.f;

#pragma unroll 8
  for (int k = 0; k < 64; ++k) {
    float a[8], b[8];
#pragma unroll
    for (int i = 0; i < 4; ++i) {
      a[i]     = Xs[(ty * 4 + i) * 65 + k];
      a[4 + i] = Xs[(64 + ty * 4 + i) * 65 + k];
    }
    float4 b0 = *reinterpret_cast<const float4*>(Ws + k * 128 + tx * 4);
    float4 b1 = *reinterpret_cast<const float4*>(Ws + k * 128 + 64 + tx * 4);
    b[0]=b0.x; b[1]=b0.y; b[2]=b0.z; b[3]=b0.w;
    b[4]=b1.x; b[5]=b1.y; b[6]=b1.z; b[7]=b1.w;
#pragma unroll
    for (int i = 0; i < 8; ++i)
#pragma unroll
      for (int j = 0; j < 8; ++j) acc[i][j] = fmaf(a[i], b[j], acc[i][j]);
  }

  if constexpr (STORE) {
    float4 sA = make_float4(1,1,1,1), bA = make_float4(0,0,0,0);
    float4 sB = sA, bB = bA;
    if constexpr (ACT) {
      sA = *reinterpret_cast<const float4*>(sc1 + col0 + tx * 4);
      bA = *reinterpret_cast<const float4*>(sh1 + col0 + tx * 4);
      sB = *reinterpret_cast<const float4*>(sc1 + col0 + 64 + tx * 4);
      bB = *reinterpret_cast<const float4*>(sh1 + col0 + 64 + tx * 4);
    }
#pragma unroll
    for (int i = 0; i < 8; ++i) {
      const int r = row0 + ((i < 4) ? (ty * 4 + i) : (64 + ty * 4 + i - 4));
      if (r < NS) {
        float4 v0 = make_float4(acc[i][0], acc[i][1], acc[i][2], acc[i][3]);
        float4 v1 = make_float4(acc[i][4], acc[i][5], acc[i][6], acc[i][7]);
        if constexpr (ACT) {
          v0.x = relu6f(fmaf(v0.x, sA.x, bA.x)); v0.y = relu6f(fmaf(v0.y, sA.y, bA.y));
          v0.z = relu6f(fmaf(v0.z, sA.z, bA.z)); v0.w = relu6f(fmaf(v0.w, sA.w, bA.w));
          v1.x = relu6f(fmaf(v1.x, sB.x, bB.x)); v1.y = relu6f(fmaf(v1.y, sB.y, bB.y));
          v1.z = relu6f(fmaf(v1.z, sB.z, bB.z)); v1.w = relu6f(fmaf(v1.w, sB.w, bB.w));
        }
        st4(t1 + (size_t)r * HID + col0 + tx * 4, v0);
        st4(t1 + (size_t)r * HID + col0 + 64 + tx * 4, v1);
      }
    }
  }

  if constexpr (!ACT) {
    float cs[8], cq[8];
#pragma unroll
    for (int j = 0; j < 8; ++j) {
      cs[j] = 0.f; cq[j] = 0.f;
#pragma unroll
      for (int i = 0; i < 8; ++i) { float v = acc[i][j]; cs[j] += v; cq[j] += v * v; }
    }
    __syncthreads();
    float* red = lds;  // [16][256]
#pragma unroll
    for (int j = 0; j < 8; ++j) {
      const int col = (j < 4) ? (tx * 4 + j) : (64 + tx * 4 + j - 4);
      red[ty * 256 + col * 2]     = cs[j];
      red[ty * 256 + col * 2 + 1] = cq[j];
    }
    __syncthreads();
    {
      float s = 0.f;
#pragma unroll
      for (int t = 0; t < 16; ++t) s += red[t * 256 + tid];
      const int col = tid >> 1, st = tid & 1;
      atomicAdd(stats1 + st * HID + col0 + col, s);
    }
  }
}

// ---------------------------------------------------------------------------
// k_act: h1u8 = quantize(relu6(bn1(t1)))  elementwise, uchar4 per thread.
// NH/4 = 19.2M threads, grid exact.
// ---------------------------------------------------------------------------
__global__ __launch_bounds__(256)
void k_act(const u16* __restrict__ t1, const float* __restrict__ sc,
           const float* __restrict__ sh, uint8_t* __restrict__ h1) {
  const size_t e = (size_t)blockIdx.x * 256 + threadIdx.x;
  const int c0 = (int)(e % 96) * 4;
  const float4 s = *reinterpret_cast<const float4*>(sc + c0);
  const float4 b = *reinterpret_cast<const float4*>(sh + c0);
  const ushort4 v = *reinterpret_cast<const ushort4*>(t1 + e * 4);
  float4 h;
  h.x = relu6f(fmaf(bf2f(v.x), s.x, b.x));
  h.y = relu6f(fmaf(bf2f(v.y), s.y, b.y));
  h.z = relu6f(fmaf(bf2f(v.z), s.z, b.z));
  h.w = relu6f(fmaf(bf2f(v.w), s.w, b.w));
  st4(h1 + e * 4, h);  // uint8 quantized store
}

// ---------------------------------------------------------------------------
// k_dwconv_u8: SINGLE gather pass over u8 h1 -> out2 bf16 + BN2 stats.
// 384 threads = 4 subs x 96 lanes (4 ch each, uchar4 loads). 64 rows/block.
// ---------------------------------------------------------------------------
__global__ __launch_bounds__(384)
void k_dwconv_u8(const uint8_t* __restrict__ h1, const int* __restrict__ nidx,
                 const uint8_t* __restrict__ cmask, const float* __restrict__ w2,
                 u16* __restrict__ out2, float* __restrict__ stats2) {
  __shared__ float red[3 * 96 * 9];
  const int tid = threadIdx.x;
  const int sub = tid / 96;          // 0..3
  const int lc  = tid - sub * 96;    // 0..95
  const int c0  = lc * 4;
  float4 w2r[KV];
#pragma unroll
  for (int k = 0; k < KV; ++k)
    w2r[k] = *reinterpret_cast<const float4*>(w2 + k * HID + c0);

  const int rowBase = blockIdx.x * 64;
  float4 sum = make_float4(0,0,0,0), sq = make_float4(0,0,0,0);
  for (int r = sub; r < 64; r += 4) {
    const int i = rowBase + r;
    const int*     ip = nidx  + (size_t)i * KV;
    const uint8_t* mp = cmask + (size_t)i * KV;
    float4 a = make_float4(0,0,0,0);
#pragma unroll
    for (int k = 0; k < KV; ++k) {
      const int j = ip[k];
      const float mk = mp[k] ? 1.f : 0.f;
      const uchar4 v = *reinterpret_cast<const uchar4*>(h1 + (size_t)j * HID + c0);
      a.x = fmaf(v.x * U8DQ, w2r[k].x * mk, a.x);
      a.y = fmaf(v.y * U8DQ, w2r[k].y * mk, a.y);
      a.z = fmaf(v.z * U8DQ, w2r[k].z * mk, a.z);
      a.w = fmaf(v.w * U8DQ, w2r[k].w * mk, a.w);
    }
    st4(out2 + (size_t)i * HID + c0, a);  // bf16 store
    sum.x += a.x; sum.y += a.y; sum.z += a.z; sum.w += a.w;
    sq.x  += a.x * a.x; sq.y += a.y * a.y; sq.z += a.z * a.z; sq.w += a.w * a.w;
  }
  if (sub > 0) {
    float* p = red + ((sub - 1) * 96 + lc) * 9;
    p[0] = sum.x; p[1] = sum.y; p[2] = sum.z; p[3] = sum.w;
    p[4] = sq.x;  p[5] = sq.y;  p[6] = sq.z;  p[7] = sq.w;
  }
  __syncthreads();
  if (sub == 0) {
#pragma unroll
    for (int s = 0; s < 3; ++s) {
      const float* p = red + (s * 96 + lc) * 9;
      sum.x += p[0]; sum.y += p[1]; sum.z += p[2]; sum.w += p[3];
      sq.x  += p[4]; sq.y  += p[5]; sq.z  += p[6]; sq.w  += p[7];
    }
    atomicAdd(stats2 + c0,     sum.x);
    atomicAdd(stats2 + c0 + 1, sum.y);
    atomicAdd(stats2 + c0 + 2, sum.z);
    atomicAdd(stats2 + c0 + 3, sum.w);
    atomicAdd(stats2 + HID + c0,     sq.x);
    atomicAdd(stats2 + HID + c0 + 1, sq.y);
    atomicAdd(stats2 + HID + c0 + 2, sq.z);
    atomicAdd(stats2 + HID + c0 + 3, sq.w);
  }
}

// ---------------------------------------------------------------------------
// Gather stats pass (tier B): out2 computed on the fly -> BN2 sum/sumsq.
// ---------------------------------------------------------------------------
template <typename T>
__global__ __launch_bounds__(384)
void k_dw_stats(const T* __restrict__ h1, const int* __restrict__ nidx,
                const uint8_t* __restrict__ cmask, const float* __restrict__ w2,
                const float* __restrict__ scale1, const float* __restrict__ shift1,
                float* __restrict__ stats2) {
  __shared__ float red[3 * 96 * 9];
  const int tid = threadIdx.x;
  const int sub = tid / 96;
  const int lc  = tid - sub * 96;
  const int c0  = lc * 4;
  const float4 s1 = *reinterpret_cast<const float4*>(scale1 + c0);
  const float4 b1 = *reinterpret_cast<const float4*>(shift1 + c0);
  float4 w2r[KV];
#pragma unroll
  for (int k = 0; k < KV; ++k)
    w2r[k] = *reinterpret_cast<const float4*>(w2 + k * HID + c0);

  const int rowBase = blockIdx.x * 64;
  float4 sum = make_float4(0,0,0,0), sq = make_float4(0,0,0,0);
  for (int r = sub; r < 64; r += 4) {
    const int i = rowBase + r;
    const int*     ip = nidx  + (size_t)i * KV;
    const uint8_t* mp = cmask + (size_t)i * KV;
    float4 a = make_float4(0,0,0,0);
#pragma unroll
    for (int k = 0; k < KV; ++k) {
      const int j = ip[k];
      const float mk = mp[k] ? 1.f : 0.f;
      float4 h = load_h4(h1 + (size_t)j * HID + c0, s1, b1);
      a.x = fmaf(h.x, w2r[k].x * mk, a.x);
      a.y = fmaf(h.y, w2r[k].y * mk, a.y);
      a.z = fmaf(h.z, w2r[k].z * mk, a.z);
      a.w = fmaf(h.w, w2r[k].w * mk, a.w);
    }
    sum.x += a.x; sum.y += a.y; sum.z += a.z; sum.w += a.w;
    sq.x  += a.x * a.x; sq.y += a.y * a.y; sq.z += a.z * a.z; sq.w += a.w * a.w;
  }
  if (sub > 0) {
    float* p = red + ((sub - 1) * 96 + lc) * 9;
    p[0] = sum.x; p[1] = sum.y; p[2] = sum.z; p[3] = sum.w;
    p[4] = sq.x;  p[5] = sq.y;  p[6] = sq.z;  p[7] = sq.w;
  }
  __syncthreads();
  if (sub == 0) {
#pragma unroll
    for (int s = 0; s < 3; ++s) {
      const float* p = red + (s * 96 + lc) * 9;
      sum.x += p[0]; sum.y += p[1]; sum.z += p[2]; sum.w += p[3];
      sq.x  += p[4]; sq.y  += p[5]; sq.z  += p[6]; sq.w  += p[7];
    }
    atomicAdd(stats2 + c0,     sum.x);
    atomicAdd(stats2 + c0 + 1, sum.y);
    atomicAdd(stats2 + c0 + 2, sum.z);
    atomicAdd(stats2 + c0 + 3, sum.w);
    atomicAdd(stats2 + HID + c0,     sq.x);
    atomicAdd(stats2 + HID + c0 + 1, sq.y);
    atomicAdd(stats2 + HID + c0 + 2, sq.z);
    atomicAdd(stats2 + HID + c0 + 3, sq.w);
  }
}

// ---------------------------------------------------------------------------
// Fused gemm3 (tier B): A-tile staged by RECOMPUTING out2 rows via gather,
// then bn2+relu6, then GEMM with w3 -> d_out + BN3 stats.
// Tile 64x64, 256 threads, 2x8 blocking. 4 blocks/CU.
// ---------------------------------------------------------------------------
template <typename T>
__global__ __launch_bounds__(256, 4)
void k_gemm3f(const T* __restrict__ h1, const int* __restrict__ nidx,
              const uint8_t* __restrict__ cmask, const float* __restrict__ w2,
              const float* __restrict__ w3,
              const float* __restrict__ sc1v, const float* __restrict__ sh1v,
              const float* __restrict__ sc2v, const float* __restrict__ sh2v,
              float* __restrict__ out, float* __restrict__ stats3) {
  __shared__ float lds[4160 + 4096 + 576];
  float* __restrict__ As  = lds;                 // [64][65]
  float* __restrict__ Ws  = lds + 4160;          // [64][64]
  float* __restrict__ W2s = lds + 4160 + 4096;   // [9][64]
  const int row0 = blockIdx.x * 64;
  const int tid  = threadIdx.x;
  const int tx = tid & 7, ty = tid >> 3;

  float acc[2][8];
#pragma unroll
  for (int i = 0; i < 2; ++i)
#pragma unroll
    for (int j = 0; j < 8; ++j) acc[i][j] = 0.f;

  for (int kc = 0; kc < HID; kc += 64) {
    if (tid < 144) {
      const int k = tid / 16, q4 = (tid & 15) * 4;
      *reinterpret_cast<float4*>(W2s + k * 64 + q4) =
          *reinterpret_cast<const float4*>(w2 + k * HID + kc + q4);
    }
    __syncthreads();

    {
      const int k4 = (tid & 15) * 4;
      const int mb = tid >> 4;
      const float4 s1 = *reinterpret_cast<const float4*>(sc1v + kc + k4);
      const float4 b1 = *reinterpret_cast<const float4*>(sh1v + kc + k4);
      const float4 s2 = *reinterpret_cast<const float4*>(sc2v + kc + k4);
      const float4 b2 = *reinterpret_cast<const float4*>(sh2v + kc + k4);
#pragma unroll
      for (int it = 0; it < 4; ++it) {
        const int m = mb + it * 16;
        const int i = row0 + m;
        const int*     ip = nidx  + (size_t)i * KV;
        const uint8_t* mp = cmask + (size_t)i * KV;
        float4 a = make_float4(0.f, 0.f, 0.f, 0.f);
#pragma unroll
        for (int k = 0; k < KV; ++k) {
          const int j = ip[k];
          const float mk = mp[k] ? 1.f : 0.f;
          float4 h = load_h4(h1 + (size_t)j * HID + kc + k4, s1, b1);
          a.x = fmaf(h.x, W2s[k * 64 + k4]     * mk, a.x);
          a.y = fmaf(h.y, W2s[k * 64 + k4 + 1] * mk, a.y);
          a.z = fmaf(h.z, W2s[k * 64 + k4 + 2] * mk, a.z);
          a.w = fmaf(h.w, W2s[k * 64 + k4 + 3] * mk, a.w);
        }
        float* p = As + m * 65 + k4;
        p[0] = relu6f(fmaf(a.x, s2.x, b2.x));
        p[1] = relu6f(fmaf(a.y, s2.y, b2.y));
        p[2] = relu6f(fmaf(a.z, s2.z, b2.z));
        p[3] = relu6f(fmaf(a.w, s2.w, b2.w));
      }
    }
    {
      const int n4 = (tid & 15) * 4;
      const int kb = tid >> 4;
#pragma unroll
      for (int it = 0; it < 4; ++it) {
        const int k = kb + it * 16;
        *reinterpret_cast<float4*>(Ws + k * 64 + n4) =
            *reinterpret_cast<const float4*>(w3 + (size_t)(kc + k) * COUT + n4);
      }
    }
    __syncthreads();

#pragma unroll 8
    for (int k = 0; k < 64; ++k) {
      float a[2], b[8];
#pragma unroll
      for (int i = 0; i < 2; ++i) a[i] = As[(ty * 2 + i) * 65 + k];
      float4 b0 = *reinterpret_cast<const float4*>(Ws + k * 64 + tx * 4);
      float4 b1 = *reinterpret_cast<const float4*>(Ws + k * 64 + 32 + tx * 4);
      b[0]=b0.x; b[1]=b0.y; b[2]=b0.z; b[3]=b0.w;
      b[4]=b1.x; b[5]=b1.y; b[6]=b1.z; b[7]=b1.w;
#pragma unroll
      for (int i = 0; i < 2; ++i)
#pragma unroll
        for (int j = 0; j < 8; ++j) acc[i][j] = fmaf(a[i], b[j], acc[i][j]);
    }
    __syncthreads();
  }

#pragma unroll
  for (int i = 0; i < 2; ++i) {
    const int r = row0 + ty * 2 + i;
    *reinterpret_cast<float4*>(out + (size_t)r * COUT + tx * 4) =
        make_float4(acc[i][0], acc[i][1], acc[i][2], acc[i][3]);
    *reinterpret_cast<float4*>(out + (size_t)r * COUT + 32 + tx * 4) =
        make_float4(acc[i][4], acc[i][5], acc[i][6], acc[i][7]);
  }

  float cs[8], cq[8];
#pragma unroll
  for (int j = 0; j < 8; ++j) {
    cs[j] = 0.f; cq[j] = 0.f;
#pragma unroll
    for (int i = 0; i < 2; ++i) { float v = acc[i][j]; cs[j] += v; cq[j] += v * v; }
  }
  __syncthreads();
  float* red = lds;
#pragma unroll
  for (int j = 0; j < 8; ++j) {
    const int col = (j < 4) ? (tx * 4 + j) : (32 + tx * 4 + j - 4);
    red[ty * 128 + col * 2]     = cs[j];
    red[ty * 128 + col * 2 + 1] = cq[j];
  }
  __syncthreads();
  if (tid < 128) {
    float s = 0.f;
#pragma unroll
    for (int t = 0; t < 32; ++t) s += red[t * 128 + tid];
    const int col = tid >> 1, st = tid & 1;
    atomicAdd(stats3 + st * COUT + col, s);
  }
}

// ---------------------------------------------------------------------------
// Linear gemm3 (tiers A/C2): reads materialized out2, bn2+relu6 on stage.
// ---------------------------------------------------------------------------
template <typename TI>
__global__ __launch_bounds__(256, 3)
void k_gemm3(const TI* __restrict__ out2, const float* __restrict__ w3,
             const float* __restrict__ scale2, const float* __restrict__ shift2,
             float* __restrict__ t3, float* __restrict__ stats3) {
  __shared__ float lds[8320 + 4096];
  float* __restrict__ As = lds;          // [128][65]
  float* __restrict__ Ws = lds + 8320;   // [64][64]
  const int row0 = blockIdx.x * 128;
  const int tid  = threadIdx.x;
  const int tx = tid & 7, ty = tid >> 3;
  float acc[4][8];
#pragma unroll
  for (int i = 0; i < 4; ++i)
#pragma unroll
    for (int j = 0; j < 8; ++j) acc[i][j] = 0.f;

  for (int kc = 0; kc < HID; kc += 64) {
    {
      const int k4 = (tid & 15) * 4;
      const int mb = tid >> 4;
      const float4 sc = *reinterpret_cast<const float4*>(scale2 + kc + k4);
      const float4 sh = *reinterpret_cast<const float4*>(shift2 + kc + k4);
#pragma unroll
      for (int it = 0; it < 8; ++it) {
        const int m = mb + it * 16;
        const int r = row0 + m;
        float4 o = make_float4(0.f, 0.f, 0.f, 0.f);
        if (r < NS) {
          const float4 v = ld4(out2 + (size_t)r * HID + kc + k4);
          o.x = relu6f(fmaf(v.x, sc.x, sh.x));
          o.y = relu6f(fmaf(v.y, sc.y, sh.y));
          o.z = relu6f(fmaf(v.z, sc.z, sh.z));
          o.w = relu6f(fmaf(v.w, sc.w, sh.w));
        }
        float* p = As + m * 65 + k4;
        p[0] = o.x; p[1] = o.y; p[2] = o.z; p[3] = o.w;
      }
    }
    {
      const int n4 = (tid & 15) * 4;
      const int kb = tid >> 4;
#pragma unroll
      for (int it = 0; it < 4; ++it) {
        const int k = kb + it * 16;
        *reinterpret_cast<float4*>(Ws + k * 64 + n4) =
            *reinterpret_cast<const float4*>(w3 + (size_t)(kc + k) * COUT + n4);
      }
    }
    __syncthreads();
#pragma unroll 8
    for (int k = 0; k < 64; ++k) {
      float a[4], b[8];
#pragma unroll
      for (int i = 0; i < 4; ++i) a[i] = As[(ty * 4 + i) * 65 + k];
      float4 b0 = *reinterpret_cast<const float4*>(Ws + k * 64 + tx * 4);
      float4 b1 = *reinterpret_cast<const float4*>(Ws + k * 64 + 32 + tx * 4);
      b[0]=b0.x; b[1]=b0.y; b[2]=b0.z; b[3]=b0.w;
      b[4]=b1.x; b[5]=b1.y; b[6]=b1.z; b[7]=b1.w;
#pragma unroll
      for (int i = 0; i < 4; ++i)
#pragma unroll
        for (int j = 0; j < 8; ++j) acc[i][j] = fmaf(a[i], b[j], acc[i][j]);
    }
    __syncthreads();
  }
#pragma unroll
  for (int i = 0; i < 4; ++i) {
    const int r = row0 + ty * 4 + i;
    if (r < NS) {
      *reinterpret_cast<float4*>(t3 + (size_t)r * COUT + tx * 4) =
          make_float4(acc[i][0], acc[i][1], acc[i][2], acc[i][3]);
      *reinterpret_cast<float4*>(t3 + (size_t)r * COUT + 32 + tx * 4) =
          make_float4(acc[i][4], acc[i][5], acc[i][6], acc[i][7]);
    }
  }
  float cs[8], cq[8];
#pragma unroll
  for (int j = 0; j < 8; ++j) {
    cs[j] = 0.f; cq[j] = 0.f;
#pragma unroll
    for (int i = 0; i < 4; ++i) { float v = acc[i][j]; cs[j] += v; cq[j] += v * v; }
  }
  __syncthreads();
  float* red = lds;
#pragma unroll
  for (int j = 0; j < 8; ++j) {
    const int col = (j < 4) ? (tx * 4 + j) : (32 + tx * 4 + j - 4);
    red[ty * 128 + col * 2]     = cs[j];
    red[ty * 128 + col * 2 + 1] = cq[j];
  }
  __syncthreads();
  if (tid < 128) {
    float s = 0.f;
#pragma unroll
    for (int t = 0; t < 32; ++t) s += red[t * 128 + tid];
    const int col = tid >> 1, st = tid & 1;
    atomicAdd(stats3 + st * COUT + col, s);
  }
}

// ---------------------------------------------------------------------------
// Tier F (tiny workspace) — unchanged recompute fallback.
// ---------------------------------------------------------------------------
__global__ __launch_bounds__(384)
void k_dw_stats_recomp(const float* __restrict__ x, const float* __restrict__ w1,
                       const int* __restrict__ nidx, const uint8_t* __restrict__ cmask,
                       const float* __restrict__ w2,
                       const float* __restrict__ scale1, const float* __restrict__ shift1,
                       float* __restrict__ stats2) {
  __shared__ u16   W1s[64 * 384];
  __shared__ float xb[KV][64];
  const int c = threadIdx.x;
#pragma unroll
  for (int it = 0; it < 16; ++it) {
    const int idx4 = it * 384 + c;
    float4 v = *reinterpret_cast<const float4*>(w1 + idx4 * 4);
    ushort4 u; u.x = f2bf(v.x); u.y = f2bf(v.y); u.z = f2bf(v.z); u.w = f2bf(v.w);
    *reinterpret_cast<ushort4*>(W1s + idx4 * 4) = u;
  }
  const float s1 = scale1[c], b1 = shift1[c];
  float w2r[KV];
#pragma unroll
  for (int k = 0; k < KV; ++k) w2r[k] = w2[k * HID + c];
  const int rowBase = blockIdx.x * 64;
  float sum = 0.f, sq = 0.f;
  for (int r = 0; r < 64; ++r) {
    const int i = rowBase + r;
    __syncthreads();
    if (c < 144) {
      const int k = c >> 4, q = c & 15;
      const int j = nidx[(size_t)i * KV + k];
      *reinterpret_cast<float4*>(&xb[k][q * 4]) =
          *reinterpret_cast<const float4*>(x + (size_t)j * CIN + q * 4);
    }
    __syncthreads();
    const uint8_t* mp = cmask + (size_t)i * KV;
    float acc = 0.f;
#pragma unroll
    for (int k = 0; k < KV; ++k) {
      if (mp[k]) {
        float t = 0.f;
#pragma unroll
        for (int kk = 0; kk < 64; ++kk)
          t = fmaf(xb[k][kk], bf2f(W1s[kk * 384 + c]), t);
        acc = fmaf(relu6f(fmaf(t, s1, b1)), w2r[k], acc);
      }
    }
    sum += acc; sq += acc * acc;
  }
  atomicAdd(stats2 + c,       sum);
  atomicAdd(stats2 + HID + c, sq);
}

__global__ __launch_bounds__(384)
void k_gemm3_recomp(const float* __restrict__ x, const float* __restrict__ w1,
                    const int* __restrict__ nidx, const uint8_t* __restrict__ cmask,
                    const float* __restrict__ w2, const float* __restrict__ w3,
                    const float* __restrict__ scale1, const float* __restrict__ shift1,
                    const float* __restrict__ scale2, const float* __restrict__ shift2,
                    float* __restrict__ out, float* __restrict__ stats3) {
  __shared__ u16   W1s[64 * 384];
  __shared__ float xb[KV][64];
  __shared__ float h2[HID];
  __shared__ float part[6][64];
  const int c = threadIdx.x;
#pragma unroll
  for (int it = 0; it < 16; ++it) {
    const int idx4 = it * 384 + c;
    float4 v = *reinterpret_cast<const float4*>(w1 + idx4 * 4);
    ushort4 u; u.x = f2bf(v.x); u.y = f2bf(v.y); u.z = f2bf(v.z); u.w = f2bf(v.w);
    *reinterpret_cast<ushort4*>(W1s + idx4 * 4) = u;
  }
  const float s1 = scale1[c], b1 = shift1[c];
  const float s2 = scale2[c], b2 = shift2[c];
  float w2r[KV];
#pragma unroll
  for (int k = 0; k < KV; ++k) w2r[k] = w2[k * HID + c];
  const int wv = c >> 6;
  const int ln = c & 63;
  float ssum = 0.f, ssq = 0.f;
  const int rowBase = blockIdx.x * 32;
  for (int r = 0; r < 32; ++r) {
    const int i = rowBase + r;
    __syncthreads();
    if (c < 144) {
      const int k = c >> 4, q = c & 15;
      const int j = nidx[(size_t)i * KV + k];
      *reinterpret_cast<float4*>(&xb[k][q * 4]) =
          *reinterpret_cast<const float4*>(x + (size_t)j * CIN + q * 4);
    }
    __syncthreads();
    const uint8_t* mp = cmask + (size_t)i * KV;
    float acc = 0.f;
#pragma unroll
    for (int k = 0; k < KV; ++k) {
      if (mp[k]) {
        float t = 0.f;
#pragma unroll
        for (int kk = 0; kk < 64; ++kk)
          t = fmaf(xb[k][kk], bf2f(W1s[kk * 384 + c]), t);
        acc = fmaf(relu6f(fmaf(t, s1, b1)), w2r[k], acc);
      }
    }
    h2[c] = relu6f(fmaf(acc, s2, b2));
    __syncthreads();
    float pt = 0.f;
#pragma unroll
    for (int cc = 0; cc < 64; ++cc) {
      const int ch = wv * 64 + cc;
      pt = fmaf(h2[ch], w3[ch * COUT + ln], pt);
    }
    part[wv][ln] = pt;
    __syncthreads();
    if (c < 64) {
      const float t3 = part[0][c] + part[1][c] + part[2][c] +
                       part[3][c] + part[4][c] + part[5][c];
      out[(size_t)i * COUT + c] = t3;
      ssum += t3; ssq += t3 * t3;
    }
  }
  if (c < 64) {
    atomicAdd(stats3 + c,        ssum);
    atomicAdd(stats3 + COUT + c, ssq);
  }
}

// ---------------------------------------------------------------------------
__global__ void k_finalize(const float* __restrict__ gamma, const float* __restrict__ beta,
                           float* __restrict__ stats, int C, float invN) {
  const int c = blockIdx.x * blockDim.x + threadIdx.x;
  if (c >= C) return;
  const float mean = stats[c] * invN;
  const float var  = stats[C + c] * invN - mean * mean;
  const float sc   = gamma[c] / sqrtf(var + BN_EPS);
  stats[2 * C + c] = sc;
  stats[3 * C + c] = fmaf(-mean, sc, beta[c]);
}

__global__ __launch_bounds__(256)
void k_final(const float* __restrict__ x, const float* __restrict__ st3,
             float* __restrict__ out) {
  const int t  = blockIdx.x * 256 + threadIdx.x;
  const int cg = (t & 15) * 4;
  const float4 v  = *reinterpret_cast<const float4*>(out + (size_t)t * 4);
  const float4 xi = *reinterpret_cast<const float4*>(x  + (size_t)t * 4);
  const float4 sc = *reinterpret_cast<const float4*>(st3 + 128 + cg);
  const float4 sh = *reinterpret_cast<const float4*>(st3 + 192 + cg);
  float4 o;
  o.x = fmaf(v.x, sc.x, sh.x) + xi.x;
  o.y = fmaf(v.y, sc.y, sh.y) + xi.y;
  o.z = fmaf(v.z, sc.z, sh.z) + xi.z;
  o.w = fmaf(v.w, sc.w, sh.w) + xi.w;
  *reinterpret_cast<float4*>(out + (size_t)t * 4) = o;
}

// ---------------------------------------------------------------------------
extern "C" void kernel_launch(void* const* d_in, const int* in_sizes, int n_in,
                              void* d_out, int out_size, void* d_ws, size_t ws_size,
                              hipStream_t stream) {
  const float* x    = (const float*)d_in[0];
  const float* w1   = (const float*)d_in[1];
  const float* g1   = (const float*)d_in[2];
  const float* b1   = (const float*)d_in[3];
  const float* w2   = (const float*)d_in[4];
  const float* g2   = (const float*)d_in[5];
  const float* b2   = (const float*)d_in[6];
  const float* w3   = (const float*)d_in[7];
  const float* g3   = (const float*)d_in[8];
  const float* b3   = (const float*)d_in[9];
  const int*   nidx = (const int*)d_in[10];
  const void*  mraw = d_in[11];
  float* out = (float*)d_out;

  const size_t NH   = (size_t)NS * HID;            // 76.8M elements
  const size_t BASE = (size_t)2 * 1024 * 1024;
  const size_t need_A  = BASE + NH * 4;            // t1 bf16 + out2 bf16 (~309 MB)
  const size_t need_C2 = BASE + NH * 3;            // t1/out2 bf16 + h1 u8 (~232 MB)
  const size_t need_B  = BASE + NH * 2;            // t1 bf16, double gather (~156 MB)
  const size_t need_D  = BASE + NH;                // h1 uint8, double gather (~79 MB)
  const size_t need_F  = BASE;                     // recompute tier (~2 MB)

  char* p = (char*)d_ws;
  float*   st    = (float*)p;                  // 3328 floats
  int*     flag  = (int*)(p + 13312);
  uint8_t* cmask = (uint8_t*)(p + 16384);      // 1.8 MB
  float* stats1 = st;          // sum[384],sq[384],scale[384],shift[384]
  float* stats2 = st + 1536;
  float* stats3 = st + 3072;
  const float invN = 1.0f / (float)NS;
  const int NKV = NS * KV;

  if (ws_size < need_F) {
    hipMemcpyAsync(d_out, d_in[0], (size_t)out_size * sizeof(float),
                   hipMemcpyDeviceToDevice, stream);
    return;
  }

  hipMemsetAsync(st, 0, 13312, stream);
  k_detect<<<1, 256, 0, stream>>>((const uint8_t*)mraw, flag);
  k_canon<<<(NKV + 255) / 256, 256, 0, stream>>>(mraw, flag, cmask, NKV);

  dim3 gA((NS + 127) / 128, HID / 128);
  const int gRows128 = (NS + 127) / 128;
  const int gRows64  = NS / 64;                // 3125, exact

  if (ws_size >= need_A) {
    // ---- tier A (ws>=309MB): same structure as tier B (proven) ----
    u16* t1 = (u16*)(p + BASE);
    k_gemm1<u16, true, false><<<gA, 256, 0, stream>>>(x, w1, t1, stats1, nullptr, nullptr);
    k_finalize<<<1, HID, 0, stream>>>(g1, b1, stats1, HID, invN);
    k_dw_stats<u16><<<gRows64, 384, 0, stream>>>(t1, nidx, cmask, w2,
                                                 stats1 + 768, stats1 + 1152, stats2);
    k_finalize<<<1, HID, 0, stream>>>(g2, b2, stats2, HID, invN);
    k_gemm3f<u16><<<gRows64, 256, 0, stream>>>(t1, nidx, cmask, w2, w3,
                                               stats1 + 768, stats1 + 1152,
                                               stats2 + 768, stats2 + 1152,
                                               out, stats3);
  } else if (ws_size >= need_C2) {
    // ---- tier C2: t1 bf16 -> h1 u8 -> SINGLE u8 gather -> out2 bf16 (over t1)
    //      -> linear gemm3 ----
    u16*     t1   = (u16*)(p + BASE);
    uint8_t* h1   = (uint8_t*)(p + BASE + NH * 2);
    u16*     out2 = (u16*)(p + BASE);            // overwrites dead t1
    k_gemm1<u16, true, false><<<gA, 256, 0, stream>>>(x, w1, t1, stats1, nullptr, nullptr);
    k_finalize<<<1, HID, 0, stream>>>(g1, b1, stats1, HID, invN);
    k_act<<<(int)(NH / 4 / 256), 256, 0, stream>>>(t1, stats1 + 768, stats1 + 1152, h1);
    k_dwconv_u8<<<gRows64, 384, 0, stream>>>(h1, nidx, cmask, w2, out2, stats2);
    k_finalize<<<1, HID, 0, stream>>>(g2, b2, stats2, HID, invN);
    k_gemm3<u16><<<gRows128, 256, 0, stream>>>(out2, w3, stats2 + 768, stats2 + 1152,
                                               out, stats3);
  } else if (ws_size >= need_B) {
    // ---- tier B: t1 bf16 materialized; out2 recomputed (double gather) ----
    u16* t1 = (u16*)(p + BASE);
    k_gemm1<u16, true, false><<<gA, 256, 0, stream>>>(x, w1, t1, stats1, nullptr, nullptr);
    k_finalize<<<1, HID, 0, stream>>>(g1, b1, stats1, HID, invN);
    k_dw_stats<u16><<<gRows64, 384, 0, stream>>>(t1, nidx, cmask, w2,
                                                 stats1 + 768, stats1 + 1152, stats2);
    k_finalize<<<1, HID, 0, stream>>>(g2, b2, stats2, HID, invN);
    k_gemm3f<u16><<<gRows64, 256, 0, stream>>>(t1, nidx, cmask, w2, w3,
                                               stats1 + 768, stats1 + 1152,
                                               stats2 + 768, stats2 + 1152,
                                               out, stats3);
  } else if (ws_size >= need_D) {
    // ---- tier D: h1 u8 only, double gather ----
    uint8_t* h1 = (uint8_t*)(p + BASE);
    k_gemm1<u16, false, false><<<gA, 256, 0, stream>>>(x, w1, (u16*)nullptr, stats1,
                                                       nullptr, nullptr);
    k_finalize<<<1, HID, 0, stream>>>(g1, b1, stats1, HID, invN);
    k_gemm1<uint8_t, true, true><<<gA, 256, 0, stream>>>(x, w1, h1, stats1,
                                                         stats1 + 768, stats1 + 1152);
    k_dw_stats<uint8_t><<<gRows64, 384, 0, stream>>>(h1, nidx, cmask, w2,
                                                     stats1 + 768, stats1 + 1152, stats2);
    k_finalize<<<1, HID, 0, stream>>>(g2, b2, stats2, HID, invN);
    k_gemm3f<uint8_t><<<gRows64, 256, 0, stream>>>(h1, nidx, cmask, w2, w3,
                                                   stats1 + 768, stats1 + 1152,
                                                   stats2 + 768, stats2 + 1152,
                                                   out, stats3);
  } else {
    // ---- tier F: tiny-workspace recompute ----
    k_gemm1<u16, false, false><<<gA, 256, 0, stream>>>(x, w1, (u16*)nullptr, stats1,
                                                       nullptr, nullptr);
    k_finalize<<<1, HID, 0, stream>>>(g1, b1, stats1, HID, invN);
    k_dw_stats_recomp<<<gRows64, HID, 0, stream>>>(x, w1, nidx, cmask, w2,
                                                   stats1 + 768, stats1 + 1152, stats2);
    k_finalize<<<1, HID, 0, stream>>>(g2, b2, stats2, HID, invN);
    k_gemm3_recomp<<<NS / 32, HID, 0, stream>>>(x, w1, nidx, cmask, w2, w3,
                                                stats1 + 768, stats1 + 1152,
                                                stats2 + 768, stats2 + 1152,
                                                out, stats3);
  }

  k_finalize<<<1, COUT, 0, stream>>>(g3, b3, stats3, COUT, invN);
  k_final<<<(NS * COUT / 4) / 256, 256, 0, stream>>>(x, stats3, out);
}